// Round 5
// baseline (333.281 us; speedup 1.0000x reference)
//
// AssociativeMemoryStep — Round 8.
// Algebraic collapse: S = (x@basis)@Mqk@(x@basis)^T and
//   out = (S@xb2) @ (o_w@vc)^T, so attention runs directly on
//   xb2 = x@basis (K and V sides) and QM = x@(basis@Mqk).
// Pipeline: prep1 (D1=kc^T@qc, D2T=vc^T@oc, bsT->Bcat[0:256)) ->
//   prep2 (BqT=D1@basis^T -> Bcat[256:512), Wvo=basis@D2) ->
//   gemm_x_fused XQ[16384,512] = x(f32) @ Bcat^T  (xb2 | QM) ->
//   transpose_x (xb2 -> VTx[B,256,T]) -> attn(Q=XQ[,256:], K=XQ[,0:256],
//   V=VTx) -> Rv -> oproj out = osc * Rv @ Wvo^T (R3-exact gemm_bt_mfma).
// R8 root-cause fix: R7's gemm1 had VGPR=60/LDS=32KB but grid 512 = 2
//   blocks/CU = 8 waves/CU -> latency-naked (Occupancy 17%). gemm_x_fused
//   uses 64x64 tiles, grid 2048 (8 blocks/CU assigned, 16KB LDS each),
//   launch_bounds(256,4) to hold VGPR<=128 -> >=16 waves/CU.
// LDS XOR swizzle (64B rows): physical 16B chunk = (logical + (row>>1)) & 3.
//   gld16 dest lane-linear => *source* permuted; frag reads use
//   fsw=((q+(lm>>1))&3)*16.  (Verified involution, unchanged.)
// Window 512: decay^511 ~ 1.7e-11 relative -> exact truncation.
#include <hip/hip_runtime.h>
#include <math.h>
#include <stdint.h>

#define B_ 4
#define T_ 4096
#define V_ 1024
#define C_ 256
#define WINDOW 512

typedef __bf16 bf16x8 __attribute__((ext_vector_type(8)));
typedef float f32x4 __attribute__((ext_vector_type(4)));
typedef unsigned short us8 __attribute__((ext_vector_type(8)));

__device__ __forceinline__ void gld16(const void* g, void* l) {
  auto gp = reinterpret_cast<const __attribute__((address_space(1))) uint32_t*>(
      reinterpret_cast<uintptr_t>(g));
  auto lp = reinterpret_cast<__attribute__((address_space(3))) uint32_t*>(
      reinterpret_cast<uintptr_t>(l));
  __builtin_amdgcn_global_load_lds(gp, lp, 16, 0, 0);
}

__device__ __forceinline__ unsigned short f2bf(float f) {
  union { float f; unsigned u; } v; v.f = f;
  unsigned r = v.u + 0x7fffu + ((v.u >> 16) & 1u);  // RNE
  return (unsigned short)(r >> 16);
}

// ---------------------------------------------------------------------------
// prep1: z==0 (16 blocks): D1[a,b] = sum_c kc[c,a]*qc[c,b]   (= Mqk^T), f32.
//        z==1 (16 blocks): D2T[a,b] = sum_c vc[c,a]*oc[c,b]  (= (oc^T@vc)^T).
//        z==2 (64 blocks): Bcat rows 0..255 = bf16(basis^T).
// ---------------------------------------------------------------------------
__global__ __launch_bounds__(256) void prep1(
    const float* __restrict__ qc, const float* __restrict__ kc,
    const float* __restrict__ vc, const float* __restrict__ oc,
    const float* __restrict__ basis, float* __restrict__ D1,
    float* __restrict__ D2T, unsigned short* __restrict__ Bcat) {
  const int tid = threadIdx.x;
  const int z = blockIdx.y;
  if (z == 2) {
    if (blockIdx.x >= 64) return;
    __shared__ unsigned short tile[64][65];
    const int rb = blockIdx.x >> 2, cb = blockIdx.x & 3;  // 16 x 4 tiles
#pragma unroll
    for (int r2 = 0; r2 < 2; ++r2) {
      const int idx = r2 * 256 + tid;
      const int row = idx >> 3, p = idx & 7;
      const float4 a = *(const float4*)(basis + (size_t)(rb * 64 + row) * 256 +
                                        cb * 64 + p * 8);
      const float4 b = *(const float4*)(basis + (size_t)(rb * 64 + row) * 256 +
                                        cb * 64 + p * 8 + 4);
      tile[row][p * 8 + 0] = f2bf(a.x); tile[row][p * 8 + 1] = f2bf(a.y);
      tile[row][p * 8 + 2] = f2bf(a.z); tile[row][p * 8 + 3] = f2bf(a.w);
      tile[row][p * 8 + 4] = f2bf(b.x); tile[row][p * 8 + 5] = f2bf(b.y);
      tile[row][p * 8 + 6] = f2bf(b.z); tile[row][p * 8 + 7] = f2bf(b.w);
    }
    __syncthreads();
#pragma unroll
    for (int r2 = 0; r2 < 2; ++r2) {
      const int idx = r2 * 256 + tid;
      const int c = idx >> 3, p = idx & 7;
      us8 v;
#pragma unroll
      for (int j = 0; j < 8; ++j) v[j] = tile[p * 8 + j][c];
      *(us8*)(Bcat + ((size_t)(cb * 64 + c)) * 1024 + rb * 64 + p * 8) = v;
    }
  } else {
    if (blockIdx.x >= 16) return;
    const float* A = (z == 0) ? kc : vc;
    const float* Bp = (z == 0) ? qc : oc;
    float* Out = (z == 0) ? D1 : D2T;
    __shared__ float As[16][65];
    __shared__ float Bs[16][65];
    const int bm = blockIdx.x >> 2, bn = blockIdx.x & 3;
    const int m0 = bm * 64, n0 = bn * 64;
    const int tm = tid >> 4, tn = tid & 15;
    float acc[4][4] = {};
    for (int k0 = 0; k0 < 256; k0 += 16) {
#pragma unroll
      for (int r = 0; r < 4; ++r) {
        const int m = (tid >> 4) + 16 * r;
        As[tid & 15][m] = A[(size_t)(k0 + (tid & 15)) * 256 + m0 + m];
        Bs[tid & 15][m] = Bp[(size_t)(k0 + (tid & 15)) * 256 + n0 + m];
      }
      __syncthreads();
#pragma unroll
      for (int k = 0; k < 16; ++k) {
        float a[4], b[4];
#pragma unroll
        for (int i = 0; i < 4; ++i) a[i] = As[k][tm * 4 + i];
#pragma unroll
        for (int j = 0; j < 4; ++j) b[j] = Bs[k][tn * 4 + j];
#pragma unroll
        for (int i = 0; i < 4; ++i)
#pragma unroll
          for (int j = 0; j < 4; ++j) acc[i][j] += a[i] * b[j];
      }
      __syncthreads();
    }
#pragma unroll
    for (int i = 0; i < 4; ++i)
#pragma unroll
      for (int j = 0; j < 4; ++j)
        Out[(size_t)(m0 + tm * 4 + i) * 256 + n0 + tn * 4 + j] = acc[i][j];
  }
}

// ---------------------------------------------------------------------------
// prep2: z==0 (64 blocks): BqT[256,1024] = D1 @ basis^T -> Bcat rows 256..511.
//        z==1 (64 blocks): Wvo[1024,256] = basis @ D2 (D2 = D2T^T).
// ---------------------------------------------------------------------------
__global__ __launch_bounds__(256) void prep2(
    const float* __restrict__ basis, const float* __restrict__ D1,
    const float* __restrict__ D2T, unsigned short* __restrict__ Bcat,
    unsigned short* __restrict__ Wvo) {
  const int tid = threadIdx.x;
  const int z = blockIdx.y;
  __shared__ float As[16][65];
  __shared__ float Bs[16][65];
  const int tm = tid >> 4, tn = tid & 15;
  float acc[4][4] = {};
  if (z == 0) {
    const int bm = blockIdx.x >> 4, bn = blockIdx.x & 15;  // 4 x 16
    const int m0 = bm * 64, n0 = bn * 64;
    for (int k0 = 0; k0 < 256; k0 += 16) {
#pragma unroll
      for (int r = 0; r < 4; ++r) {
        const int m = (tid >> 4) + 16 * r;
        As[tid & 15][m] = D1[(size_t)(m0 + m) * 256 + k0 + (tid & 15)];
        Bs[tid & 15][m] = basis[(size_t)(n0 + m) * 256 + k0 + (tid & 15)];
      }
      __syncthreads();
#pragma unroll
      for (int k = 0; k < 16; ++k) {
        float a[4], b[4];
#pragma unroll
        for (int i = 0; i < 4; ++i) a[i] = As[k][tm * 4 + i];
#pragma unroll
        for (int j = 0; j < 4; ++j) b[j] = Bs[k][tn * 4 + j];
#pragma unroll
        for (int i = 0; i < 4; ++i)
#pragma unroll
          for (int j = 0; j < 4; ++j) acc[i][j] += a[i] * b[j];
      }
      __syncthreads();
    }
#pragma unroll
    for (int i = 0; i < 4; ++i)
#pragma unroll
      for (int j = 0; j < 4; ++j)
        Bcat[(size_t)(256 + m0 + tm * 4 + i) * 1024 + n0 + tn * 4 + j] =
            f2bf(acc[i][j]);
  } else {
    const int bm = blockIdx.x >> 2, bn = blockIdx.x & 3;  // 16 x 4
    const int m0 = bm * 64, n0 = bn * 64;
    for (int k0 = 0; k0 < 256; k0 += 16) {
#pragma unroll
      for (int r = 0; r < 4; ++r) {
        const int m = (tid >> 4) + 16 * r;
        As[tid & 15][m] = basis[(size_t)(m0 + m) * 256 + k0 + (tid & 15)];
        Bs[tid & 15][m] = D2T[(size_t)(n0 + m) * 256 + k0 + (tid & 15)];
      }
      __syncthreads();
#pragma unroll
      for (int k = 0; k < 16; ++k) {
        float a[4], b[4];
#pragma unroll
        for (int i = 0; i < 4; ++i) a[i] = As[k][tm * 4 + i];
#pragma unroll
        for (int j = 0; j < 4; ++j) b[j] = Bs[k][tn * 4 + j];
#pragma unroll
        for (int i = 0; i < 4; ++i)
#pragma unroll
          for (int j = 0; j < 4; ++j) acc[i][j] += a[i] * b[j];
      }
      __syncthreads();
    }
#pragma unroll
    for (int i = 0; i < 4; ++i)
#pragma unroll
      for (int j = 0; j < 4; ++j)
        Wvo[(size_t)(m0 + tm * 4 + i) * 256 + n0 + tn * 4 + j] =
            f2bf(acc[i][j]);
  }
}

// ---------------------------------------------------------------------------
// gemm_x_fused: XQ[16384,512] = x(f32)[16384,1024] @ Bcat[512,1024]^T (bf16).
// Tile 64m x 64n, BK=64, 16 iters, 256 thr = 4 waves (2m x 2n), wave 32x32,
// acc[2][2]. Grid 2048 = 8 blocks/CU assigned; launch_bounds(256,4) caps
// VGPR<=128 (>=16 waves/CU resident). xcd=g&7 owns m-tiles [32*xcd,+32).
// A: per-lane direct global fp32 frag loads -> v_cvt bf16 (no LDS), 1-ahead.
// B: double-buffered LDS (2 x 8KB; two 64B-row kk sub-tiles), gld16 with
//   source-permuted XOR swizzle, staged 1 tile ahead (issue-early).
// ---------------------------------------------------------------------------
__global__ __launch_bounds__(256, 4) void gemm_x_fused(
    const float* __restrict__ X, const unsigned short* __restrict__ Bc,
    unsigned short* __restrict__ XQ) {
  __shared__ __align__(16) unsigned short Bs[2][2][64 * 32];  // 16KB
  const int tid = threadIdx.x;
  const int g = blockIdx.x;
  const int xcd = g & 7, loc = g >> 3;                // 0..255
  const int m0 = (xcd * 32 + (loc >> 3)) * 64;
  const int n0 = (loc & 7) * 64;
  const int w = tid >> 6, l = tid & 63, q = l >> 4, lm = l & 15;
  const int wm = w >> 1, wn = w & 1;
  const f32x4 zero4 = {0.f, 0.f, 0.f, 0.f};
  f32x4 acc[2][2];
#pragma unroll
  for (int i = 0; i < 2; ++i)
#pragma unroll
    for (int j = 0; j < 2; ++j) acc[i][j] = zero4;

  const int rowB = tid >> 2;
  const int cph = (tid & 3) * 16;                         // physical chunk
  const int clg = (((tid & 3) - (rowB >> 1)) & 3) * 16;   // logical source
  const int fsw = ((q + (lm >> 1)) & 3) * 16;             // frag-read swizzle

  const float* Ag = X + (size_t)(m0 + wm * 32 + lm) * 1024 + q * 8;
  f32x4 aR[2][2][2];  // [mt][kk][half] fp32 staging for tile t

  auto stageB = [&](int t) {
    const char* Bg =
        (const char*)Bc + ((size_t)(n0 + rowB) * 1024) * 2 + t * 128 + clg;
    gld16(Bg, (char*)&Bs[t & 1][0][0] + rowB * 64 + cph);
    gld16(Bg + 64, (char*)&Bs[t & 1][1][0] + rowB * 64 + cph);
  };
  auto loadA = [&](int t) {
#pragma unroll
    for (int mt = 0; mt < 2; ++mt)
#pragma unroll
      for (int kk = 0; kk < 2; ++kk) {
        const float* p = Ag + (size_t)mt * 16 * 1024 + t * 64 + kk * 32;
        aR[mt][kk][0] = *(const f32x4*)(p);
        aR[mt][kk][1] = *(const f32x4*)(p + 4);
      }
  };

  stageB(0);
  loadA(0);

  for (int t = 0; t < 16; ++t) {
    __syncthreads();  // drains tile-t gld16+A loads (issued a phase ago)
    if (t < 15) stageB(t + 1);
    bf16x8 af[2][2];
#pragma unroll
    for (int mt = 0; mt < 2; ++mt)
#pragma unroll
      for (int kk = 0; kk < 2; ++kk)
#pragma unroll
        for (int j = 0; j < 4; ++j) {
          af[mt][kk][j] = (__bf16)aR[mt][kk][0][j];
          af[mt][kk][4 + j] = (__bf16)aR[mt][kk][1][j];
        }
    if (t < 15) loadA(t + 1);  // issued now, drained at next barrier
    bf16x8 bf[2][2];
#pragma unroll
    for (int nt = 0; nt < 2; ++nt)
#pragma unroll
      for (int kk = 0; kk < 2; ++kk)
        bf[nt][kk] = *(const bf16x8*)((const char*)&Bs[t & 1][kk][0] +
                                      (wn * 32 + nt * 16 + lm) * 64 + fsw);
#pragma unroll
    for (int mt = 0; mt < 2; ++mt)
#pragma unroll
      for (int nt = 0; nt < 2; ++nt) {
        acc[mt][nt] = __builtin_amdgcn_mfma_f32_16x16x32_bf16(
            af[mt][0], bf[nt][0], acc[mt][nt], 0, 0, 0);
        acc[mt][nt] = __builtin_amdgcn_mfma_f32_16x16x32_bf16(
            af[mt][1], bf[nt][1], acc[mt][nt], 0, 0, 0);
      }
  }
#pragma unroll
  for (int mt = 0; mt < 2; ++mt)
#pragma unroll
    for (int nt = 0; nt < 2; ++nt)
#pragma unroll
      for (int r = 0; r < 4; ++r) {
        const int row = m0 + wm * 32 + mt * 16 + q * 4 + r;
        const int col = n0 + wn * 32 + nt * 16 + lm;
        XQ[(size_t)row * 512 + col] = f2bf(acc[mt][nt][r]);
      }
}

// ---------------------------------------------------------------------------
// bf16 MFMA GEMM, C = alpha * A[M,K] * B[N,K]^T. 128x128 tile, BK=32.
// (R3-exact proven kernel.) 1D grid = nT*128 blocks; XCD swizzle: xcd=g&7
// owns m-tiles [16*xcd,16*xcd+16) x all n. LDS XOR-swizzled, conflict-free.
// ---------------------------------------------------------------------------
__global__ __launch_bounds__(256) void gemm_bt_mfma(
    const unsigned short* __restrict__ A, const unsigned short* __restrict__ Bm,
    void* __restrict__ Cp, int Kd, int N, int nT, int outBf16,
    const float* __restrict__ alphaPtr) {
  __shared__ __align__(16) unsigned short As[128 * 32];
  __shared__ __align__(16) unsigned short Bs[128 * 32];
  const int tid = threadIdx.x;
  const int g = blockIdx.x;
  const int xcd = g & 7, loc = g >> 3;
  const int n0 = (loc % nT) * 128;
  const int m0 = (xcd * 16 + loc / nT) * 128;
  const int w = tid >> 6, l = tid & 63, q = l >> 4, lm = l & 15;
  const int wm = w >> 1, wn = w & 1;
  const f32x4 zero4 = {0.f, 0.f, 0.f, 0.f};
  f32x4 acc[4][4];
#pragma unroll
  for (int i = 0; i < 4; ++i)
#pragma unroll
    for (int j = 0; j < 4; ++j) acc[i][j] = zero4;

  const int rowA = tid >> 2;
  const int cph = (tid & 3) * 16;                         // physical chunk
  const int clg = (((tid & 3) - (rowA >> 1)) & 3) * 16;   // logical source
  const int fsw = ((q + (lm >> 1)) & 3) * 16;             // frag-read swizzle

  for (int k0 = 0; k0 < Kd; k0 += 32) {
    __syncthreads();
    const char* Ag = (const char*)A + ((size_t)(m0 + rowA) * Kd + k0) * 2 + clg;
    const char* Bg = (const char*)Bm + ((size_t)(n0 + rowA) * Kd + k0) * 2 + clg;
    gld16(Ag, (char*)As + rowA * 64 + cph);
    gld16(Ag + (size_t)64 * Kd * 2, (char*)As + (64 + rowA) * 64 + cph);
    gld16(Bg, (char*)Bs + rowA * 64 + cph);
    gld16(Bg + (size_t)64 * Kd * 2, (char*)Bs + (64 + rowA) * 64 + cph);
    __syncthreads();
    bf16x8 af[4], bf[4];
#pragma unroll
    for (int mt = 0; mt < 4; ++mt)
      af[mt] = *(const bf16x8*)((const char*)As +
                                (wm * 64 + mt * 16 + lm) * 64 + fsw);
#pragma unroll
    for (int nt = 0; nt < 4; ++nt)
      bf[nt] = *(const bf16x8*)((const char*)Bs +
                                (wn * 64 + nt * 16 + lm) * 64 + fsw);
#pragma unroll
    for (int mt = 0; mt < 4; ++mt)
#pragma unroll
      for (int nt = 0; nt < 4; ++nt)
        acc[mt][nt] = __builtin_amdgcn_mfma_f32_16x16x32_bf16(
            af[mt], bf[nt], acc[mt][nt], 0, 0, 0);
  }
  const float alpha = alphaPtr ? alphaPtr[0] : 1.0f;
#pragma unroll
  for (int mt = 0; mt < 4; ++mt)
#pragma unroll
    for (int nt = 0; nt < 4; ++nt)
#pragma unroll
      for (int r = 0; r < 4; ++r) {
        const int row = m0 + wm * 64 + mt * 16 + q * 4 + r;
        const int col = n0 + wn * 64 + nt * 16 + lm;
        const float vv = acc[mt][nt][r] * alpha;
        if (outBf16)
          ((unsigned short*)Cp)[(size_t)row * N + col] = f2bf(vv);
        else
          ((float*)Cp)[(size_t)row * N + col] = vv;
      }
}

// ---------------------------------------------------------------------------
// Transpose xb2 slice of XQ: XQ[b*T+t][c<256] -> VTx[b][c][t]. 64x64 tiles.
// ---------------------------------------------------------------------------
__global__ __launch_bounds__(256) void transpose_x(
    const unsigned short* __restrict__ XQ, unsigned short* __restrict__ VT) {
  __shared__ unsigned short tile[64][65];
  const int tb = blockIdx.x, cb = blockIdx.y, b = blockIdx.z;
  const int tid = threadIdx.x;
#pragma unroll
  for (int r2 = 0; r2 < 2; ++r2) {
    const int idx = r2 * 256 + tid;
    const int row = idx >> 3, p = idx & 7;
    const us8 v = *(const us8*)(XQ +
        ((size_t)(b * T_ + tb * 64 + row)) * 512 + cb * 64 + p * 8);
#pragma unroll
    for (int j = 0; j < 8; ++j) tile[row][p * 8 + j] = v[j];
  }
  __syncthreads();
#pragma unroll
  for (int r2 = 0; r2 < 2; ++r2) {
    const int idx = r2 * 256 + tid;
    const int c = idx >> 3, p = idx & 7;
    us8 v;
#pragma unroll
    for (int j = 0; j < 8; ++j) v[j] = tile[p * 8 + j][c];
    *(us8*)(VT + ((size_t)b * C_ + cb * 64 + c) * T_ + tb * 64 + p * 8) = v;
  }
}

// ---------------------------------------------------------------------------
// Windowed anti-causal decayed attention on the collapsed basis:
//   S = QM @ xb2^T (K-dim 256), Rv = (S.*decay) @ xb2 (via VTx).
// t-tile 32, s-tile 64, 256 thr. Structure identical to the proven R3 attn;
// only pointers/strides changed (XQ row = 512 us: cols 0-255 = xb2 = K/V,
// cols 256-511 = QM = Q).
// ---------------------------------------------------------------------------
__global__ __launch_bounds__(256) void attn_mfma(
    const unsigned short* __restrict__ XQ, const unsigned short* __restrict__ VTx,
    const float* __restrict__ dlp, unsigned short* __restrict__ Rv) {
  __shared__ __align__(16) unsigned short Kst[16384];  // 32KB
  __shared__ __align__(16) unsigned short Vst[8192];   // 16KB (V half)
  __shared__ __align__(16) unsigned short Ss[32 * 72]; // 4.5KB

  const int g = blockIdx.x;
  const int chunk = (g & 7) * 64 + (g >> 3);
  const int b = chunk >> 7;
  const int t0 = (chunk & 127) << 5;
  const int tid = threadIdx.x;
  const int w = tid >> 6, l = tid & 63, q = l >> 4, lm = l & 15;
  const float dec = 1.f / (1.f + __expf(-dlp[0]));
  const float l2d = log2f(dec);
  const unsigned short* XQb = XQ + (size_t)b * T_ * 512;
  const int fsw = ((q + (lm >> 1)) & 3) * 16;

  // ---- stage Q [ch8][row32][64B] (16KB) swizzled, extract frags ----
  {
    const char* Qg = (const char*)(XQb + (size_t)t0 * 512) + 512;  // QM cols
#pragma unroll
    for (int p = 0; p < 4; ++p) {
      const int o = (p * 256 + tid) * 16;
      const int ch = o >> 11, row = (o >> 6) & 31;
      const int clg = ((((o >> 4) & 3) - (row >> 1)) & 3) * 16;
      gld16(Qg + (size_t)row * 1024 + ch * 64 + clg, (char*)Kst + o);
    }
  }
  __syncthreads();
  bf16x8 qf[2][8];
#pragma unroll
  for (int mt = 0; mt < 2; ++mt)
#pragma unroll
    for (int ch = 0; ch < 8; ++ch)
      qf[mt][ch] = *(const bf16x8*)((const char*)Kst + ch * 2048 +
                                    (mt * 16 + lm) * 64 + fsw);

  const f32x4 zero4 = {0.f, 0.f, 0.f, 0.f};
  f32x4 acc[2][4];
#pragma unroll
  for (int i = 0; i < 2; ++i)
#pragma unroll
    for (int j = 0; j < 4; ++j) acc[i][j] = zero4;

  const int st0 = t0 >> 6;
  const int st1 = min(T_ / 64 - 1, (t0 + 31 + WINDOW) >> 6);
  const char* Kg = (const char*)XQb;  // xb2 cols 0-255 = K rows
  const char* Vg = (const char*)(VTx + (size_t)b * C_ * T_);

  for (int st = st0; st <= st1; ++st) {
    const int s0 = st << 6;
    __syncthreads();  // A: prior readers of Kst/Vst/Ss done
#pragma unroll
    for (int p = 0; p < 8; ++p) {  // K tile [ch8][row64][64B]
      const int o = (p * 256 + tid) * 16;
      const int ch = o >> 12, row = (o >> 6) & 63;
      const int clg = ((((o >> 4) & 3) - (row >> 1)) & 3) * 16;
      gld16(Kg + (size_t)(s0 + row) * 1024 + ch * 64 + clg, (char*)Kst + o);
    }
#pragma unroll
    for (int p = 0; p < 4; ++p) {  // V half 0: s0..s0+31
      const int o = (p * 256 + tid) * 16;
      const int c = o >> 6;
      const int clg8 = (((o >> 4) & 3) - (c >> 1)) & 3;
      gld16(Vg + ((size_t)c * T_ + s0 + clg8 * 8) * 2, (char*)Vst + o);
    }
    __syncthreads();  // B: K + Vh0 visible

    // ---- QK^T: wave w -> s-cols [s0+16w, s0+16w+16), both mt tiles ----
    f32x4 sc[2] = {zero4, zero4};
#pragma unroll
    for (int ch = 0; ch < 8; ++ch) {
      const bf16x8 kf = *(const bf16x8*)((const char*)Kst + ch * 4096 +
                                         (w * 16 + lm) * 64 + fsw);
      sc[0] = __builtin_amdgcn_mfma_f32_16x16x32_bf16(qf[0][ch], kf, sc[0], 0, 0, 0);
      sc[1] = __builtin_amdgcn_mfma_f32_16x16x32_bf16(qf[1][ch], kf, sc[1], 0, 0, 0);
    }
    // ---- decay*mask in C-layout, bf16 scores to LDS ----
    const int sg = s0 + w * 16 + lm;
#pragma unroll
    for (int mt = 0; mt < 2; ++mt)
#pragma unroll
      for (int r = 0; r < 4; ++r) {
        const int trow = t0 + mt * 16 + q * 4 + r;
        const int d = sg - trow;
        const float wgt = (d > 0) ? exp2f(l2d * (float)(d - 1)) : 0.f;
        Ss[(mt * 16 + q * 4 + r) * 72 + w * 16 + lm] = f2bf(sc[mt][r] * wgt);
      }
    __syncthreads();  // C: Ss visible
    bf16x8 sa[2][2];
#pragma unroll
    for (int m2 = 0; m2 < 2; ++m2)
#pragma unroll
      for (int kc2 = 0; kc2 < 2; ++kc2)
        sa[m2][kc2] = *(const bf16x8*)&Ss[(m2 * 16 + lm) * 72 + kc2 * 32 + q * 8];
    // ---- S*V, k-half 0: wave w -> channels 64w..64w+63 ----
#pragma unroll
    for (int n2 = 0; n2 < 4; ++n2) {
      const bf16x8 vf = *(const bf16x8*)((const char*)Vst +
                                         (w * 64 + n2 * 16 + lm) * 64 + fsw);
      acc[0][n2] = __builtin_amdgcn_mfma_f32_16x16x32_bf16(sa[0][0], vf, acc[0][n2], 0, 0, 0);
      acc[1][n2] = __builtin_amdgcn_mfma_f32_16x16x32_bf16(sa[1][0], vf, acc[1][n2], 0, 0, 0);
    }
    __syncthreads();  // D: Vh0 consumed
#pragma unroll
    for (int p = 0; p < 4; ++p) {  // V half 1: s0+32..s0+63
      const int o = (p * 256 + tid) * 16;
      const int c = o >> 6;
      const int clg8 = (((o >> 4) & 3) - (c >> 1)) & 3;
      gld16(Vg + ((size_t)c * T_ + s0 + 32 + clg8 * 8) * 2, (char*)Vst + o);
    }
    __syncthreads();  // E: Vh1 visible
#pragma unroll
    for (int n2 = 0; n2 < 4; ++n2) {
      const bf16x8 vf = *(const bf16x8*)((const char*)Vst +
                                         (w * 64 + n2 * 16 + lm) * 64 + fsw);
      acc[0][n2] = __builtin_amdgcn_mfma_f32_16x16x32_bf16(sa[0][1], vf, acc[0][n2], 0, 0, 0);
      acc[1][n2] = __builtin_amdgcn_mfma_f32_16x16x32_bf16(sa[1][1], vf, acc[1][n2], 0, 0, 0);
    }
  }
  // epilogue
#pragma unroll
  for (int m2 = 0; m2 < 2; ++m2)
#pragma unroll
    for (int n2 = 0; n2 < 4; ++n2)
#pragma unroll
      for (int r = 0; r < 4; ++r) {
        const int row = t0 + m2 * 16 + q * 4 + r;
        const int col = w * 64 + n2 * 16 + lm;
        Rv[((size_t)b * T_ + row) * C_ + col] = f2bf(acc[m2][n2][r]);
      }
}

// ---------------------------------------------------------------------------
extern "C" void kernel_launch(void* const* d_in, const int* in_sizes, int n_in,
                              void* d_out, int out_size, void* d_ws,
                              size_t ws_size, hipStream_t stream) {
  const float* x     = (const float*)d_in[0];
  const float* basis = (const float*)d_in[1];
  const float* qc    = (const float*)d_in[2];
  const float* kc    = (const float*)d_in[3];
  const float* vc    = (const float*)d_in[4];
  const float* oc    = (const float*)d_in[5];
  const float* dl    = (const float*)d_in[6];
  const float* osc   = (const float*)d_in[7];
  float* out = (float*)d_out;

  unsigned short* ws = (unsigned short*)d_ws;
  const size_t MSZ = (size_t)B_ * T_ * C_;                // 4.19M
  unsigned short* XQ   = ws;                              // [16384,512]
  unsigned short* VTx  = XQ + (size_t)16384 * 512;        // [B,256,T]
  unsigned short* Rv   = VTx + MSZ;                       // [B*T,256]
  unsigned short* Bcat = Rv + MSZ;                        // [512,1024]
  unsigned short* Wvo  = Bcat + 512 * 1024;               // [1024,256]
  float* D1  = (float*)(Wvo + 1024 * 256);                // [256,256] f32
  float* D2T = D1 + 256 * 256;                            // [256,256] f32

  prep1<<<dim3(64, 3), 256, 0, stream>>>(qc, kc, vc, oc, basis, D1, D2T, Bcat);
  prep2<<<dim3(64, 2), 256, 0, stream>>>(basis, D1, D2T, Bcat, Wvo);
  // XQ = x @ [basis | basis@Mqk] : [16384,1024](f32) x [512,1024]^T -> bf16
  gemm_x_fused<<<dim3(2048), 256, 0, stream>>>(x, Bcat, XQ);
  transpose_x<<<dim3(T_ / 64, C_ / 64, B_), 256, 0, stream>>>(XQ, VTx);
  attn_mfma<<<dim3((T_ / 32) * B_), 256, 0, stream>>>(XQ, VTx, dl, Rv);
  // out = out_scale * Rv @ Wvo^T : [16384,256] x [1024,256]^T -> fp32
  gemm_bt_mfma<<<dim3(1024), 256, 0, stream>>>(Rv, Wvo, out, C_, V_, 8, 0, osc);
}

// Round 6
// 265.525 us; speedup vs baseline: 1.2552x; 1.2552x over previous
//
// AssociativeMemoryStep — Round 9.
// Algebra (R8, verified): S = QM@xb2^T, Rv = (S.*decay)@xb2, out = Rv@Wvo^T,
//   where xb2 = x@basis, QM = x@(basis@Mqk), Mqk = qc^T@kc, Wvo = basis@D2T^T.
// Pipeline (5 launches): prep1 (D1,D2T,bsT) -> prep2 (BqT,Wvo) ->
//   gemm_x_fused XQ[16384,512] = x(f32)@Bcat^T + fused VTx transpose ->
//   attn(Q=XQ[,256:], K=XQ[,:256], V=VTx) -> oproj (R3-exact gemm_bt_mfma).
// R9 fixes R8's spill: gemm_x_fused reverts to R6's PROVEN A-in-LDS 64x128
//   structure (VGPR~48, no reg-staged A, no launch_bounds cap), N=512 ->
//   grid 1024 = 4 blocks/CU. QKV gemm eliminated by the N=512 fusion; the
//   V-transpose is fused into the gemm epilogue (n0<256 blocks also write
//   VTx[b][c][t] as 8B stores along t). 7 -> 5 launches (~10us bubble each).
// LDS XOR swizzle (64B rows): physical 16B chunk = (logical + (row>>1)) & 3.
//   gld16 dest lane-linear => *source* permuted; frag reads use
//   fsw=((q+(lm>>1))&3)*16.  (Verified involution, unchanged.)
// Window 512: decay^511 ~ 1.7e-11 relative -> exact truncation.
#include <hip/hip_runtime.h>
#include <math.h>
#include <stdint.h>

#define B_ 4
#define T_ 4096
#define V_ 1024
#define C_ 256
#define WINDOW 512

typedef __bf16 bf16x8 __attribute__((ext_vector_type(8)));
typedef float f32x4 __attribute__((ext_vector_type(4)));
typedef unsigned short us8 __attribute__((ext_vector_type(8)));
typedef unsigned short us4 __attribute__((ext_vector_type(4)));

__device__ __forceinline__ void gld16(const void* g, void* l) {
  auto gp = reinterpret_cast<const __attribute__((address_space(1))) uint32_t*>(
      reinterpret_cast<uintptr_t>(g));
  auto lp = reinterpret_cast<__attribute__((address_space(3))) uint32_t*>(
      reinterpret_cast<uintptr_t>(l));
  __builtin_amdgcn_global_load_lds(gp, lp, 16, 0, 0);
}

__device__ __forceinline__ unsigned short f2bf(float f) {
  union { float f; unsigned u; } v; v.f = f;
  unsigned r = v.u + 0x7fffu + ((v.u >> 16) & 1u);  // RNE
  return (unsigned short)(r >> 16);
}

// ---------------------------------------------------------------------------
// prep1: z==0 (16 blocks): D1[a,b] = sum_c kc[c,a]*qc[c,b]   (= Mqk^T), f32.
//        z==1 (16 blocks): D2T[a,b] = sum_c vc[c,a]*oc[c,b]  (= vc^T@oc).
//        z==2 (64 blocks): Bcat rows 0..255 = bf16(basis^T).
// ---------------------------------------------------------------------------
__global__ __launch_bounds__(256) void prep1(
    const float* __restrict__ qc, const float* __restrict__ kc,
    const float* __restrict__ vc, const float* __restrict__ oc,
    const float* __restrict__ basis, float* __restrict__ D1,
    float* __restrict__ D2T, unsigned short* __restrict__ Bcat) {
  const int tid = threadIdx.x;
  const int z = blockIdx.y;
  if (z == 2) {
    if (blockIdx.x >= 64) return;
    __shared__ unsigned short tile[64][65];
    const int rb = blockIdx.x >> 2, cb = blockIdx.x & 3;  // 16 x 4 tiles
#pragma unroll
    for (int r2 = 0; r2 < 2; ++r2) {
      const int idx = r2 * 256 + tid;
      const int row = idx >> 3, p = idx & 7;
      const float4 a = *(const float4*)(basis + (size_t)(rb * 64 + row) * 256 +
                                        cb * 64 + p * 8);
      const float4 b = *(const float4*)(basis + (size_t)(rb * 64 + row) * 256 +
                                        cb * 64 + p * 8 + 4);
      tile[row][p * 8 + 0] = f2bf(a.x); tile[row][p * 8 + 1] = f2bf(a.y);
      tile[row][p * 8 + 2] = f2bf(a.z); tile[row][p * 8 + 3] = f2bf(a.w);
      tile[row][p * 8 + 4] = f2bf(b.x); tile[row][p * 8 + 5] = f2bf(b.y);
      tile[row][p * 8 + 6] = f2bf(b.z); tile[row][p * 8 + 7] = f2bf(b.w);
    }
    __syncthreads();
#pragma unroll
    for (int r2 = 0; r2 < 2; ++r2) {
      const int idx = r2 * 256 + tid;
      const int c = idx >> 3, p = idx & 7;
      us8 v;
#pragma unroll
      for (int j = 0; j < 8; ++j) v[j] = tile[p * 8 + j][c];
      *(us8*)(Bcat + ((size_t)(cb * 64 + c)) * 1024 + rb * 64 + p * 8) = v;
    }
  } else {
    if (blockIdx.x >= 16) return;
    const float* A = (z == 0) ? kc : vc;
    const float* Bp = (z == 0) ? qc : oc;
    float* Out = (z == 0) ? D1 : D2T;
    __shared__ float As[16][65];
    __shared__ float Bs[16][65];
    const int bm = blockIdx.x >> 2, bn = blockIdx.x & 3;
    const int m0 = bm * 64, n0 = bn * 64;
    const int tm = tid >> 4, tn = tid & 15;
    float acc[4][4] = {};
    for (int k0 = 0; k0 < 256; k0 += 16) {
#pragma unroll
      for (int r = 0; r < 4; ++r) {
        const int m = (tid >> 4) + 16 * r;
        As[tid & 15][m] = A[(size_t)(k0 + (tid & 15)) * 256 + m0 + m];
        Bs[tid & 15][m] = Bp[(size_t)(k0 + (tid & 15)) * 256 + n0 + m];
      }
      __syncthreads();
#pragma unroll
      for (int k = 0; k < 16; ++k) {
        float a[4], b[4];
#pragma unroll
        for (int i = 0; i < 4; ++i) a[i] = As[k][tm * 4 + i];
#pragma unroll
        for (int j = 0; j < 4; ++j) b[j] = Bs[k][tn * 4 + j];
#pragma unroll
        for (int i = 0; i < 4; ++i)
#pragma unroll
          for (int j = 0; j < 4; ++j) acc[i][j] += a[i] * b[j];
      }
      __syncthreads();
    }
#pragma unroll
    for (int i = 0; i < 4; ++i)
#pragma unroll
      for (int j = 0; j < 4; ++j)
        Out[(size_t)(m0 + tm * 4 + i) * 256 + n0 + tn * 4 + j] = acc[i][j];
  }
}

// ---------------------------------------------------------------------------
// prep2: z==0 (64 blocks): BqT[256,1024] = D1 @ basis^T -> Bcat rows 256..511.
//        z==1 (64 blocks): Wvo[1024,256] = basis @ D2T^T.
// ---------------------------------------------------------------------------
__global__ __launch_bounds__(256) void prep2(
    const float* __restrict__ basis, const float* __restrict__ D1,
    const float* __restrict__ D2T, unsigned short* __restrict__ Bcat,
    unsigned short* __restrict__ Wvo) {
  const int tid = threadIdx.x;
  const int z = blockIdx.y;
  __shared__ float As[16][65];
  __shared__ float Bs[16][65];
  const int tm = tid >> 4, tn = tid & 15;
  float acc[4][4] = {};
  if (z == 0) {
    const int bm = blockIdx.x >> 4, bn = blockIdx.x & 15;  // 4 x 16
    const int m0 = bm * 64, n0 = bn * 64;
    for (int k0 = 0; k0 < 256; k0 += 16) {
#pragma unroll
      for (int r = 0; r < 4; ++r) {
        const int m = (tid >> 4) + 16 * r;
        As[tid & 15][m] = D1[(size_t)(m0 + m) * 256 + k0 + (tid & 15)];
        Bs[tid & 15][m] = basis[(size_t)(n0 + m) * 256 + k0 + (tid & 15)];
      }
      __syncthreads();
#pragma unroll
      for (int k = 0; k < 16; ++k) {
        float a[4], b[4];
#pragma unroll
        for (int i = 0; i < 4; ++i) a[i] = As[k][tm * 4 + i];
#pragma unroll
        for (int j = 0; j < 4; ++j) b[j] = Bs[k][tn * 4 + j];
#pragma unroll
        for (int i = 0; i < 4; ++i)
#pragma unroll
          for (int j = 0; j < 4; ++j) acc[i][j] += a[i] * b[j];
      }
      __syncthreads();
    }
#pragma unroll
    for (int i = 0; i < 4; ++i)
#pragma unroll
      for (int j = 0; j < 4; ++j)
        Bcat[(size_t)(256 + m0 + tm * 4 + i) * 1024 + n0 + tn * 4 + j] =
            f2bf(acc[i][j]);
  } else {
    const int bm = blockIdx.x >> 2, bn = blockIdx.x & 3;  // 16 x 4
    const int m0 = bm * 64, n0 = bn * 64;
    for (int k0 = 0; k0 < 256; k0 += 16) {
#pragma unroll
      for (int r = 0; r < 4; ++r) {
        const int m = (tid >> 4) + 16 * r;
        As[tid & 15][m] = basis[(size_t)(m0 + m) * 256 + k0 + (tid & 15)];
        Bs[tid & 15][m] = D2T[(size_t)(n0 + m) * 256 + k0 + (tid & 15)];
      }
      __syncthreads();
#pragma unroll
      for (int k = 0; k < 16; ++k) {
        float a[4], b[4];
#pragma unroll
        for (int i = 0; i < 4; ++i) a[i] = As[k][tm * 4 + i];
#pragma unroll
        for (int j = 0; j < 4; ++j) b[j] = Bs[k][tn * 4 + j];
#pragma unroll
        for (int i = 0; i < 4; ++i)
#pragma unroll
          for (int j = 0; j < 4; ++j) acc[i][j] += a[i] * b[j];
      }
      __syncthreads();
    }
#pragma unroll
    for (int i = 0; i < 4; ++i)
#pragma unroll
      for (int j = 0; j < 4; ++j)
        Wvo[(size_t)(m0 + tm * 4 + i) * 256 + n0 + tn * 4 + j] =
            f2bf(acc[i][j]);
  }
}

// ---------------------------------------------------------------------------
// gemm_x_fused: XQ[16384,512] = x(f32)[16384,1024] @ Bcat[512,1024]^T (bf16),
// plus fused transpose: blocks with n0<256 also write VTx[b][col][t].
// R6-PROVEN structure: tile 64m x 128n, BK=32, 256 thr = 4 waves (2m x 2n),
// wave 32x64, acc[2][4], A staged fp32->regs(1-ahead)->f2bf->swizzled
// ds_write (VGPR ~48, no spill), B via source-permuted gld16.
// Grid 1024 = 4 blocks/CU; xcd=g&7 owns m-tiles [32*xcd,+32).
// ---------------------------------------------------------------------------
__global__ __launch_bounds__(256) void gemm_x_fused(
    const float* __restrict__ X, const unsigned short* __restrict__ Bc,
    unsigned short* __restrict__ XQ, unsigned short* __restrict__ VTx) {
  __shared__ __align__(16) unsigned short As[64 * 32];    // 4KB
  __shared__ __align__(16) unsigned short Bs[128 * 32];   // 8KB
  const int tid = threadIdx.x;
  const int g = blockIdx.x;
  const int xcd = g & 7, loc = g >> 3;          // loc in [0,128)
  const int m0 = (xcd * 32 + (loc >> 2)) * 64;
  const int n0 = (loc & 3) * 128;
  const int w = tid >> 6, l = tid & 63, q = l >> 4, lm = l & 15;
  const int wm = w >> 1, wn = w & 1;
  const f32x4 zero4 = {0.f, 0.f, 0.f, 0.f};
  f32x4 acc[2][4];
#pragma unroll
  for (int i = 0; i < 2; ++i)
#pragma unroll
    for (int j = 0; j < 4; ++j) acc[i][j] = zero4;

  const int arow = tid >> 2, alc = tid & 3;        // A: 64 rows x 4 chunks
  const int apc = (alc + (arow >> 1)) & 3;         // physical chunk (swizzle)
  const int rowB = tid >> 2;
  const int cph = (tid & 3) * 16;
  const int clg = (((tid & 3) - (rowB >> 1)) & 3) * 16;
  const int fsw = ((q + (lm >> 1)) & 3) * 16;

  const float* Ag = X + (size_t)(m0 + arow) * 1024 + alc * 8;
  float4 p0 = *(const float4*)(Ag);
  float4 p1 = *(const float4*)(Ag + 4);

  for (int t = 0; t < 32; ++t) {
    const int k0 = t * 32;
    __syncthreads();  // prior frag reads done
    // A write: cvt the prefetched fp32 slice, store to swizzled chunk
    us8 o;
    o[0] = f2bf(p0.x); o[1] = f2bf(p0.y); o[2] = f2bf(p0.z); o[3] = f2bf(p0.w);
    o[4] = f2bf(p1.x); o[5] = f2bf(p1.y); o[6] = f2bf(p1.z); o[7] = f2bf(p1.w);
    *(us8*)((char*)As + arow * 64 + apc * 16) = o;
    // B stage (tile t), source-permuted gld16 (Bcat stride 1024 us)
    const char* Bg =
        (const char*)Bc + ((size_t)(n0 + rowB) * 1024 + k0) * 2 + clg;
    gld16(Bg, (char*)Bs + rowB * 64 + cph);
    gld16(Bg + (size_t)64 * 2048, (char*)Bs + (64 + rowB) * 64 + cph);
    // prefetch A for t+1 (full compute phase of slack)
    if (t < 31) {
      p0 = *(const float4*)(Ag + k0 + 32);
      p1 = *(const float4*)(Ag + k0 + 36);
    }
    __syncthreads();  // drains ds_write (lgkm) + gld16/prefetch (vmcnt)
    bf16x8 af[2], bf[4];
#pragma unroll
    for (int mt = 0; mt < 2; ++mt)
      af[mt] = *(const bf16x8*)((const char*)As +
                                (wm * 32 + mt * 16 + lm) * 64 + fsw);
#pragma unroll
    for (int nt = 0; nt < 4; ++nt)
      bf[nt] = *(const bf16x8*)((const char*)Bs +
                                (wn * 64 + nt * 16 + lm) * 64 + fsw);
#pragma unroll
    for (int mt = 0; mt < 2; ++mt)
#pragma unroll
      for (int nt = 0; nt < 4; ++nt)
        acc[mt][nt] = __builtin_amdgcn_mfma_f32_16x16x32_bf16(
            af[mt], bf[nt], acc[mt][nt], 0, 0, 0);
  }
  // epilogue: XQ row-major; n0<256 blocks also write transposed VTx
#pragma unroll
  for (int mt = 0; mt < 2; ++mt)
#pragma unroll
    for (int nt = 0; nt < 4; ++nt) {
      const int row = m0 + wm * 32 + mt * 16 + q * 4;
      const int col = n0 + wn * 64 + nt * 16 + lm;
      us4 tv;
#pragma unroll
      for (int r = 0; r < 4; ++r) {
        const unsigned short hv = f2bf(acc[mt][nt][r]);
        XQ[(size_t)(row + r) * 512 + col] = hv;
        tv[r] = hv;
      }
      if (n0 < 256)
        *(us4*)(VTx + ((size_t)(row >> 12) * C_ + col) * T_ + (row & 4095)) =
            tv;
    }
}

// ---------------------------------------------------------------------------
// bf16 MFMA GEMM, C = alpha * A[M,K] * B[N,K]^T. 128x128 tile, BK=32.
// (R3-exact proven kernel.) 1D grid = nT*128 blocks; XCD swizzle: xcd=g&7
// owns m-tiles [16*xcd,16*xcd+16) x all n. LDS XOR-swizzled, conflict-free.
// ---------------------------------------------------------------------------
__global__ __launch_bounds__(256) void gemm_bt_mfma(
    const unsigned short* __restrict__ A, const unsigned short* __restrict__ Bm,
    void* __restrict__ Cp, int Kd, int N, int nT, int outBf16,
    const float* __restrict__ alphaPtr) {
  __shared__ __align__(16) unsigned short As[128 * 32];
  __shared__ __align__(16) unsigned short Bs[128 * 32];
  const int tid = threadIdx.x;
  const int g = blockIdx.x;
  const int xcd = g & 7, loc = g >> 3;
  const int n0 = (loc % nT) * 128;
  const int m0 = (xcd * 16 + loc / nT) * 128;
  const int w = tid >> 6, l = tid & 63, q = l >> 4, lm = l & 15;
  const int wm = w >> 1, wn = w & 1;
  const f32x4 zero4 = {0.f, 0.f, 0.f, 0.f};
  f32x4 acc[4][4];
#pragma unroll
  for (int i = 0; i < 4; ++i)
#pragma unroll
    for (int j = 0; j < 4; ++j) acc[i][j] = zero4;

  const int rowA = tid >> 2;
  const int cph = (tid & 3) * 16;                         // physical chunk
  const int clg = (((tid & 3) - (rowA >> 1)) & 3) * 16;   // logical source
  const int fsw = ((q + (lm >> 1)) & 3) * 16;             // frag-read swizzle

  for (int k0 = 0; k0 < Kd; k0 += 32) {
    __syncthreads();
    const char* Ag = (const char*)A + ((size_t)(m0 + rowA) * Kd + k0) * 2 + clg;
    const char* Bg = (const char*)Bm + ((size_t)(n0 + rowA) * Kd + k0) * 2 + clg;
    gld16(Ag, (char*)As + rowA * 64 + cph);
    gld16(Ag + (size_t)64 * Kd * 2, (char*)As + (64 + rowA) * 64 + cph);
    gld16(Bg, (char*)Bs + rowA * 64 + cph);
    gld16(Bg + (size_t)64 * Kd * 2, (char*)Bs + (64 + rowA) * 64 + cph);
    __syncthreads();
    bf16x8 af[4], bf[4];
#pragma unroll
    for (int mt = 0; mt < 4; ++mt)
      af[mt] = *(const bf16x8*)((const char*)As +
                                (wm * 64 + mt * 16 + lm) * 64 + fsw);
#pragma unroll
    for (int nt = 0; nt < 4; ++nt)
      bf[nt] = *(const bf16x8*)((const char*)Bs +
                                (wn * 64 + nt * 16 + lm) * 64 + fsw);
#pragma unroll
    for (int mt = 0; mt < 4; ++mt)
#pragma unroll
      for (int nt = 0; nt < 4; ++nt)
        acc[mt][nt] = __builtin_amdgcn_mfma_f32_16x16x32_bf16(
            af[mt], bf[nt], acc[mt][nt], 0, 0, 0);
  }
  const float alpha = alphaPtr ? alphaPtr[0] : 1.0f;
#pragma unroll
  for (int mt = 0; mt < 4; ++mt)
#pragma unroll
    for (int nt = 0; nt < 4; ++nt)
#pragma unroll
      for (int r = 0; r < 4; ++r) {
        const int row = m0 + wm * 64 + mt * 16 + q * 4 + r;
        const int col = n0 + wn * 64 + nt * 16 + lm;
        const float vv = acc[mt][nt][r] * alpha;
        if (outBf16)
          ((unsigned short*)Cp)[(size_t)row * N + col] = f2bf(vv);
        else
          ((float*)Cp)[(size_t)row * N + col] = vv;
      }
}

// ---------------------------------------------------------------------------
// Windowed anti-causal decayed attention on the collapsed basis:
//   S = QM @ xb2^T (K-dim 256), Rv = (S.*decay) @ xb2 (via VTx).
// t-tile 32, s-tile 64, 256 thr. (R8-exact structure; passed.)
// XQ row = 512 us: cols 0-255 = xb2 = K/V, cols 256-511 = QM = Q.
// ---------------------------------------------------------------------------
__global__ __launch_bounds__(256) void attn_mfma(
    const unsigned short* __restrict__ XQ, const unsigned short* __restrict__ VTx,
    const float* __restrict__ dlp, unsigned short* __restrict__ Rv) {
  __shared__ __align__(16) unsigned short Kst[16384];  // 32KB
  __shared__ __align__(16) unsigned short Vst[8192];   // 16KB (V half)
  __shared__ __align__(16) unsigned short Ss[32 * 72]; // 4.5KB

  const int g = blockIdx.x;
  const int chunk = (g & 7) * 64 + (g >> 3);
  const int b = chunk >> 7;
  const int t0 = (chunk & 127) << 5;
  const int tid = threadIdx.x;
  const int w = tid >> 6, l = tid & 63, q = l >> 4, lm = l & 15;
  const float dec = 1.f / (1.f + __expf(-dlp[0]));
  const float l2d = log2f(dec);
  const unsigned short* XQb = XQ + (size_t)b * T_ * 512;
  const int fsw = ((q + (lm >> 1)) & 3) * 16;

  // ---- stage Q [ch8][row32][64B] (16KB) swizzled, extract frags ----
  {
    const char* Qg = (const char*)(XQb + (size_t)t0 * 512) + 512;  // QM cols
#pragma unroll
    for (int p = 0; p < 4; ++p) {
      const int o = (p * 256 + tid) * 16;
      const int ch = o >> 11, row = (o >> 6) & 31;
      const int clg = ((((o >> 4) & 3) - (row >> 1)) & 3) * 16;
      gld16(Qg + (size_t)row * 1024 + ch * 64 + clg, (char*)Kst + o);
    }
  }
  __syncthreads();
  bf16x8 qf[2][8];
#pragma unroll
  for (int mt = 0; mt < 2; ++mt)
#pragma unroll
    for (int ch = 0; ch < 8; ++ch)
      qf[mt][ch] = *(const bf16x8*)((const char*)Kst + ch * 2048 +
                                    (mt * 16 + lm) * 64 + fsw);

  const f32x4 zero4 = {0.f, 0.f, 0.f, 0.f};
  f32x4 acc[2][4];
#pragma unroll
  for (int i = 0; i < 2; ++i)
#pragma unroll
    for (int j = 0; j < 4; ++j) acc[i][j] = zero4;

  const int st0 = t0 >> 6;
  const int st1 = min(T_ / 64 - 1, (t0 + 31 + WINDOW) >> 6);
  const char* Kg = (const char*)XQb;  // xb2 cols 0-255 = K rows
  const char* Vg = (const char*)(VTx + (size_t)b * C_ * T_);

  for (int st = st0; st <= st1; ++st) {
    const int s0 = st << 6;
    __syncthreads();  // A: prior readers of Kst/Vst/Ss done
#pragma unroll
    for (int p = 0; p < 8; ++p) {  // K tile [ch8][row64][64B]
      const int o = (p * 256 + tid) * 16;
      const int ch = o >> 12, row = (o >> 6) & 63;
      const int clg = ((((o >> 4) & 3) - (row >> 1)) & 3) * 16;
      gld16(Kg + (size_t)(s0 + row) * 1024 + ch * 64 + clg, (char*)Kst + o);
    }
#pragma unroll
    for (int p = 0; p < 4; ++p) {  // V half 0: s0..s0+31
      const int o = (p * 256 + tid) * 16;
      const int c = o >> 6;
      const int clg8 = (((o >> 4) & 3) - (c >> 1)) & 3;
      gld16(Vg + ((size_t)c * T_ + s0 + clg8 * 8) * 2, (char*)Vst + o);
    }
    __syncthreads();  // B: K + Vh0 visible

    // ---- QK^T: wave w -> s-cols [s0+16w, s0+16w+16), both mt tiles ----
    f32x4 sc[2] = {zero4, zero4};
#pragma unroll
    for (int ch = 0; ch < 8; ++ch) {
      const bf16x8 kf = *(const bf16x8*)((const char*)Kst + ch * 4096 +
                                         (w * 16 + lm) * 64 + fsw);
      sc[0] = __builtin_amdgcn_mfma_f32_16x16x32_bf16(qf[0][ch], kf, sc[0], 0, 0, 0);
      sc[1] = __builtin_amdgcn_mfma_f32_16x16x32_bf16(qf[1][ch], kf, sc[1], 0, 0, 0);
    }
    // ---- decay*mask in C-layout, bf16 scores to LDS ----
    const int sg = s0 + w * 16 + lm;
#pragma unroll
    for (int mt = 0; mt < 2; ++mt)
#pragma unroll
      for (int r = 0; r < 4; ++r) {
        const int trow = t0 + mt * 16 + q * 4 + r;
        const int d = sg - trow;
        const float wgt = (d > 0) ? exp2f(l2d * (float)(d - 1)) : 0.f;
        Ss[(mt * 16 + q * 4 + r) * 72 + w * 16 + lm] = f2bf(sc[mt][r] * wgt);
      }
    __syncthreads();  // C: Ss visible
    bf16x8 sa[2][2];
#pragma unroll
    for (int m2 = 0; m2 < 2; ++m2)
#pragma unroll
      for (int kc2 = 0; kc2 < 2; ++kc2)
        sa[m2][kc2] = *(const bf16x8*)&Ss[(m2 * 16 + lm) * 72 + kc2 * 32 + q * 8];
    // ---- S*V, k-half 0: wave w -> channels 64w..64w+63 ----
#pragma unroll
    for (int n2 = 0; n2 < 4; ++n2) {
      const bf16x8 vf = *(const bf16x8*)((const char*)Vst +
                                         (w * 64 + n2 * 16 + lm) * 64 + fsw);
      acc[0][n2] = __builtin_amdgcn_mfma_f32_16x16x32_bf16(sa[0][0], vf, acc[0][n2], 0, 0, 0);
      acc[1][n2] = __builtin_amdgcn_mfma_f32_16x16x32_bf16(sa[1][0], vf, acc[1][n2], 0, 0, 0);
    }
    __syncthreads();  // D: Vh0 consumed
#pragma unroll
    for (int p = 0; p < 4; ++p) {  // V half 1: s0+32..s0+63
      const int o = (p * 256 + tid) * 16;
      const int c = o >> 6;
      const int clg8 = (((o >> 4) & 3) - (c >> 1)) & 3;
      gld16(Vg + ((size_t)c * T_ + s0 + 32 + clg8 * 8) * 2, (char*)Vst + o);
    }
    __syncthreads();  // E: Vh1 visible
#pragma unroll
    for (int n2 = 0; n2 < 4; ++n2) {
      const bf16x8 vf = *(const bf16x8*)((const char*)Vst +
                                         (w * 64 + n2 * 16 + lm) * 64 + fsw);
      acc[0][n2] = __builtin_amdgcn_mfma_f32_16x16x32_bf16(sa[0][1], vf, acc[0][n2], 0, 0, 0);
      acc[1][n2] = __builtin_amdgcn_mfma_f32_16x16x32_bf16(sa[1][1], vf, acc[1][n2], 0, 0, 0);
    }
  }
  // epilogue
#pragma unroll
  for (int m2 = 0; m2 < 2; ++m2)
#pragma unroll
    for (int n2 = 0; n2 < 4; ++n2)
#pragma unroll
      for (int r = 0; r < 4; ++r) {
        const int row = t0 + m2 * 16 + q * 4 + r;
        const int col = w * 64 + n2 * 16 + lm;
        Rv[((size_t)b * T_ + row) * C_ + col] = f2bf(acc[m2][n2][r]);
      }
}

// ---------------------------------------------------------------------------
extern "C" void kernel_launch(void* const* d_in, const int* in_sizes, int n_in,
                              void* d_out, int out_size, void* d_ws,
                              size_t ws_size, hipStream_t stream) {
  const float* x     = (const float*)d_in[0];
  const float* basis = (const float*)d_in[1];
  const float* qc    = (const float*)d_in[2];
  const float* kc    = (const float*)d_in[3];
  const float* vc    = (const float*)d_in[4];
  const float* oc    = (const float*)d_in[5];
  const float* dl    = (const float*)d_in[6];
  const float* osc   = (const float*)d_in[7];
  float* out = (float*)d_out;

  unsigned short* ws = (unsigned short*)d_ws;
  const size_t MSZ = (size_t)B_ * T_ * C_;                // 4.19M
  unsigned short* XQ   = ws;                              // [16384,512]
  unsigned short* VTx  = XQ + (size_t)16384 * 512;        // [B,256,T]
  unsigned short* Rv   = VTx + MSZ;                       // [B*T,256]
  unsigned short* Bcat = Rv + MSZ;                        // [512,1024]
  unsigned short* Wvo  = Bcat + 512 * 1024;               // [1024,256]
  float* D1  = (float*)(Wvo + 1024 * 256);                // [256,256] f32
  float* D2T = D1 + 256 * 256;                            // [256,256] f32

  prep1<<<dim3(64, 3), 256, 0, stream>>>(qc, kc, vc, oc, basis, D1, D2T, Bcat);
  prep2<<<dim3(64, 2), 256, 0, stream>>>(basis, D1, D2T, Bcat, Wvo);
  // XQ = x @ [basis | basis@Mqk]^T + fused VTx transpose
  gemm_x_fused<<<dim3(1024), 256, 0, stream>>>(x, Bcat, XQ, VTx);
  attn_mfma<<<dim3((T_ / 32) * B_), 256, 0, stream>>>(XQ, VTx, dl, Rv);
  // out = out_scale * Rv @ Wvo^T : [16384,256] x [1024,256]^T -> fp32
  gemm_bt_mfma<<<dim3(1024), 256, 0, stream>>>(Rv, Wvo, out, C_, V_, 8, 0, osc);
}

// Round 7
// 229.482 us; speedup vs baseline: 1.4523x; 1.1571x over previous
//
// AssociativeMemoryStep — Round 10.
// R10 = R6-exact pipeline (best measured: 223.6us) with ONE counter-backed
//   change: gemm_x_basis retiled 64x128/grid-512 (2 blk/CU) -> 64x64/grid-1024
//   (4 blk/CU). R9 measured 3.69 us/GF at 4 blk/CU vs 4.94 at 2 (TLP was the
//   front GEMM's binding constraint, not scheduling — R4/R5/R7 nulls).
//   R8/R9's XQ-layout attn correlated with +42us twice -> reverted to the
//   proven QKV[q|k|v,768-stride] attn + separate transpose_v.
// Pipeline: prep_casts (W3 cast | bsT transpose) -> weights_o ->
//   gemm_x_basis xb2 = x(f32)@bsT^T -> QKV = xb2@W3^T (gemm_bt_mfma) ->
//   transpose_v -> attn -> O-proj (gemm_bt_mfma).
// LDS XOR swizzle (64B rows): physical 16B chunk = (logical + (row>>1)) & 3.
//   gld16 dest lane-linear => *source* permuted; frag reads use
//   fsw=((q+(lm>>1))&3)*16.  (Verified involution, unchanged.)
// Window 512: decay^511 ~ 1.7e-11 relative -> exact truncation.
#include <hip/hip_runtime.h>
#include <math.h>
#include <stdint.h>

#define B_ 4
#define T_ 4096
#define V_ 1024
#define C_ 256
#define WINDOW 512

typedef __bf16 bf16x8 __attribute__((ext_vector_type(8)));
typedef float f32x4 __attribute__((ext_vector_type(4)));
typedef unsigned short us8 __attribute__((ext_vector_type(8)));

__device__ __forceinline__ void gld16(const void* g, void* l) {
  auto gp = reinterpret_cast<const __attribute__((address_space(1))) uint32_t*>(
      reinterpret_cast<uintptr_t>(g));
  auto lp = reinterpret_cast<__attribute__((address_space(3))) uint32_t*>(
      reinterpret_cast<uintptr_t>(l));
  __builtin_amdgcn_global_load_lds(gp, lp, 16, 0, 0);
}

__device__ __forceinline__ unsigned short f2bf(float f) {
  union { float f; unsigned u; } v; v.f = f;
  unsigned r = v.u + 0x7fffu + ((v.u >> 16) & 1u);  // RNE
  return (unsigned short)(r >> 16);
}

// ---------------------------------------------------------------------------
// prep_casts: y==0: W3[768,256] = bf16(concat(qc,kc,vc)) — raw coeffs.
//             y==1 (blocks 0..63): bsT[256,1024] = bf16(basis^T).
// ---------------------------------------------------------------------------
__global__ __launch_bounds__(256) void prep_casts(
    const float* __restrict__ qc, const float* __restrict__ kc,
    const float* __restrict__ vc, const float* __restrict__ basis,
    unsigned short* __restrict__ W3, unsigned short* __restrict__ bsT) {
  __shared__ unsigned short tile[64][65];
  const int tid = threadIdx.x;
  if (blockIdx.y == 0) {
    const size_t i = ((size_t)blockIdx.x * 256 + tid) * 8;  // < 196608
    const float* src = (i < 65536) ? qc + i
                     : (i < 131072) ? kc + (i - 65536) : vc + (i - 131072);
    const float4 a = *(const float4*)src;
    const float4 b = *(const float4*)(src + 4);
    us8 o;
    o[0] = f2bf(a.x); o[1] = f2bf(a.y); o[2] = f2bf(a.z); o[3] = f2bf(a.w);
    o[4] = f2bf(b.x); o[5] = f2bf(b.y); o[6] = f2bf(b.z); o[7] = f2bf(b.w);
    *(us8*)(W3 + i) = o;
  } else {
    if (blockIdx.x >= 64) return;
    const int rb = blockIdx.x >> 2, cb = blockIdx.x & 3;  // 16 x 4 tiles of 64
#pragma unroll
    for (int r2 = 0; r2 < 2; ++r2) {
      const int idx = r2 * 256 + tid;
      const int row = idx >> 3, p = idx & 7;
      const float4 a = *(const float4*)(basis + (size_t)(rb * 64 + row) * 256 +
                                        cb * 64 + p * 8);
      const float4 b = *(const float4*)(basis + (size_t)(rb * 64 + row) * 256 +
                                        cb * 64 + p * 8 + 4);
      tile[row][p * 8 + 0] = f2bf(a.x); tile[row][p * 8 + 1] = f2bf(a.y);
      tile[row][p * 8 + 2] = f2bf(a.z); tile[row][p * 8 + 3] = f2bf(a.w);
      tile[row][p * 8 + 4] = f2bf(b.x); tile[row][p * 8 + 5] = f2bf(b.y);
      tile[row][p * 8 + 6] = f2bf(b.z); tile[row][p * 8 + 7] = f2bf(b.w);
    }
    __syncthreads();
#pragma unroll
    for (int r2 = 0; r2 < 2; ++r2) {
      const int idx = r2 * 256 + tid;
      const int c = idx >> 3, p = idx & 7;
      us8 v;
#pragma unroll
      for (int j = 0; j < 8; ++j) v[j] = tile[p * 8 + j][c];
      *(us8*)(bsT + ((size_t)(cb * 64 + c)) * 1024 + rb * 64 + p * 8) = v;
    }
  }
}

// ---------------------------------------------------------------------------
// weights_o: owb[1024,256] = bf16(basis @ oc^T). Grid 64 (16 x 4 tiles of 64).
// ---------------------------------------------------------------------------
__global__ __launch_bounds__(256) void weights_o(
    const float* __restrict__ basis, const float* __restrict__ oc,
    unsigned short* __restrict__ owb) {
  const int bm = blockIdx.x >> 2, bn = blockIdx.x & 3;
  const int m0 = bm * 64, n0 = bn * 64;
  __shared__ float As[16][65];
  __shared__ float Bs[16][65];
  const int tid = threadIdx.x;
  const int tm = tid >> 4, tn = tid & 15;
  float acc[4][4] = {};
  for (int k0 = 0; k0 < 256; k0 += 16) {
#pragma unroll
    for (int r = 0; r < 4; ++r) {
      const int m = (tid >> 4) + 16 * r;
      As[tid & 15][m] = basis[(size_t)(m0 + m) * 256 + k0 + (tid & 15)];
      Bs[tid & 15][m] = oc[(size_t)(n0 + m) * 256 + k0 + (tid & 15)];
    }
    __syncthreads();
#pragma unroll
    for (int k = 0; k < 16; ++k) {
      float a[4], b[4];
#pragma unroll
      for (int i = 0; i < 4; ++i) a[i] = As[k][tm * 4 + i];
#pragma unroll
      for (int j = 0; j < 4; ++j) b[j] = Bs[k][tn * 4 + j];
#pragma unroll
      for (int i = 0; i < 4; ++i)
#pragma unroll
        for (int j = 0; j < 4; ++j) acc[i][j] += a[i] * b[j];
    }
    __syncthreads();
  }
#pragma unroll
  for (int i = 0; i < 4; ++i)
#pragma unroll
    for (int j = 0; j < 4; ++j)
      owb[(size_t)(m0 + tm * 4 + i) * 256 + n0 + tn * 4 + j] = f2bf(acc[i][j]);
}

// ---------------------------------------------------------------------------
// GEMM1: xb2 = x(f32)[16384,1024] @ bsT(bf16)[256,1024]^T -> bf16 [16384,256].
// R10: tile 64m x 64n, BK=32, 256 thr = 4 waves (2m x 2n), wave 32x32,
// acc[2][2]. Grid 1024 (= 4 blocks/CU, R9-measured 3.69us/GF vs 4.94 at 2).
// xcd=g&7 owns m-tiles [32*xcd,+32) -> x slice L2-local per XCD.
// A: fp32 -> regs (prefetched 1 k-step ahead) -> f2bf -> swizzled ds_write.
// B: gld16 direct, source-permuted. 2-barrier structure (proven family).
// ---------------------------------------------------------------------------
__global__ __launch_bounds__(256) void gemm_x_basis(
    const float* __restrict__ X, const unsigned short* __restrict__ BT,
    unsigned short* __restrict__ Cp) {
  __shared__ __align__(16) unsigned short As[64 * 32];    // 4KB
  __shared__ __align__(16) unsigned short Bs[64 * 32];    // 4KB
  const int tid = threadIdx.x;
  const int g = blockIdx.x;
  const int xcd = g & 7, loc = g >> 3;         // loc in [0,128)
  const int m0 = (xcd * 32 + (loc >> 2)) * 64;
  const int n0 = (loc & 3) * 64;
  const int w = tid >> 6, l = tid & 63, q = l >> 4, lm = l & 15;
  const int wm = w >> 1, wn = w & 1;
  const f32x4 zero4 = {0.f, 0.f, 0.f, 0.f};
  f32x4 acc[2][2];
#pragma unroll
  for (int i = 0; i < 2; ++i)
#pragma unroll
    for (int j = 0; j < 2; ++j) acc[i][j] = zero4;

  const int arow = tid >> 2, alc = tid & 3;        // A: 64 rows x 4 chunks
  const int apc = (alc + (arow >> 1)) & 3;         // physical chunk (swizzle)
  const int rowB = tid >> 2;
  const int cph = (tid & 3) * 16;
  const int clg = (((tid & 3) - (rowB >> 1)) & 3) * 16;
  const int fsw = ((q + (lm >> 1)) & 3) * 16;

  const float* Ag = X + (size_t)(m0 + arow) * 1024 + alc * 8;
  float4 p0 = *(const float4*)(Ag);
  float4 p1 = *(const float4*)(Ag + 4);

  for (int t = 0; t < 32; ++t) {
    const int k0 = t * 32;
    __syncthreads();  // prior frag reads done
    // A write: cvt the prefetched fp32 slice, store to swizzled chunk
    us8 o;
    o[0] = f2bf(p0.x); o[1] = f2bf(p0.y); o[2] = f2bf(p0.z); o[3] = f2bf(p0.w);
    o[4] = f2bf(p1.x); o[5] = f2bf(p1.y); o[6] = f2bf(p1.z); o[7] = f2bf(p1.w);
    *(us8*)((char*)As + arow * 64 + apc * 16) = o;
    // B stage (tile t), source-permuted gld16
    const char* Bg =
        (const char*)BT + ((size_t)(n0 + rowB) * 1024 + k0) * 2 + clg;
    gld16(Bg, (char*)Bs + rowB * 64 + cph);
    // prefetch A for t+1 (full compute phase of slack)
    if (t < 31) {
      p0 = *(const float4*)(Ag + k0 + 32);
      p1 = *(const float4*)(Ag + k0 + 36);
    }
    __syncthreads();  // drains ds_write (lgkm) + gld16/prefetch (vmcnt)
    bf16x8 af[2], bf[2];
#pragma unroll
    for (int mt = 0; mt < 2; ++mt)
      af[mt] = *(const bf16x8*)((const char*)As +
                                (wm * 32 + mt * 16 + lm) * 64 + fsw);
#pragma unroll
    for (int nt = 0; nt < 2; ++nt)
      bf[nt] = *(const bf16x8*)((const char*)Bs +
                                (wn * 32 + nt * 16 + lm) * 64 + fsw);
#pragma unroll
    for (int mt = 0; mt < 2; ++mt)
#pragma unroll
      for (int nt = 0; nt < 2; ++nt)
        acc[mt][nt] = __builtin_amdgcn_mfma_f32_16x16x32_bf16(
            af[mt], bf[nt], acc[mt][nt], 0, 0, 0);
  }
#pragma unroll
  for (int mt = 0; mt < 2; ++mt)
#pragma unroll
    for (int nt = 0; nt < 2; ++nt)
#pragma unroll
      for (int r = 0; r < 4; ++r) {
        const int row = m0 + wm * 32 + mt * 16 + q * 4 + r;
        const int col = n0 + wn * 32 + nt * 16 + lm;
        Cp[(size_t)row * 256 + col] = f2bf(acc[mt][nt][r]);
      }
}

// ---------------------------------------------------------------------------
// bf16 MFMA GEMM, C = alpha * A[M,K] * B[N,K]^T. 128x128 tile, BK=32.
// (R3-exact proven kernel.) 1D grid = nT*128 blocks; XCD swizzle: xcd=g&7
// owns m-tiles [16*xcd,16*xcd+16) x all n. LDS XOR-swizzled, conflict-free.
// ---------------------------------------------------------------------------
__global__ __launch_bounds__(256) void gemm_bt_mfma(
    const unsigned short* __restrict__ A, const unsigned short* __restrict__ Bm,
    void* __restrict__ Cp, int Kd, int N, int nT, int outBf16,
    const float* __restrict__ alphaPtr) {
  __shared__ __align__(16) unsigned short As[128 * 32];
  __shared__ __align__(16) unsigned short Bs[128 * 32];
  const int tid = threadIdx.x;
  const int g = blockIdx.x;
  const int xcd = g & 7, loc = g >> 3;
  const int n0 = (loc % nT) * 128;
  const int m0 = (xcd * 16 + loc / nT) * 128;
  const int w = tid >> 6, l = tid & 63, q = l >> 4, lm = l & 15;
  const int wm = w >> 1, wn = w & 1;
  const f32x4 zero4 = {0.f, 0.f, 0.f, 0.f};
  f32x4 acc[4][4];
#pragma unroll
  for (int i = 0; i < 4; ++i)
#pragma unroll
    for (int j = 0; j < 4; ++j) acc[i][j] = zero4;

  const int rowA = tid >> 2;
  const int cph = (tid & 3) * 16;                         // physical chunk
  const int clg = (((tid & 3) - (rowA >> 1)) & 3) * 16;   // logical source
  const int fsw = ((q + (lm >> 1)) & 3) * 16;             // frag-read swizzle

  for (int k0 = 0; k0 < Kd; k0 += 32) {
    __syncthreads();
    const char* Ag = (const char*)A + ((size_t)(m0 + rowA) * Kd + k0) * 2 + clg;
    const char* Bg = (const char*)Bm + ((size_t)(n0 + rowA) * Kd + k0) * 2 + clg;
    gld16(Ag, (char*)As + rowA * 64 + cph);
    gld16(Ag + (size_t)64 * Kd * 2, (char*)As + (64 + rowA) * 64 + cph);
    gld16(Bg, (char*)Bs + rowA * 64 + cph);
    gld16(Bg + (size_t)64 * Kd * 2, (char*)Bs + (64 + rowA) * 64 + cph);
    __syncthreads();
    bf16x8 af[4], bf[4];
#pragma unroll
    for (int mt = 0; mt < 4; ++mt)
      af[mt] = *(const bf16x8*)((const char*)As +
                                (wm * 64 + mt * 16 + lm) * 64 + fsw);
#pragma unroll
    for (int nt = 0; nt < 4; ++nt)
      bf[nt] = *(const bf16x8*)((const char*)Bs +
                                (wn * 64 + nt * 16 + lm) * 64 + fsw);
#pragma unroll
    for (int mt = 0; mt < 4; ++mt)
#pragma unroll
      for (int nt = 0; nt < 4; ++nt)
        acc[mt][nt] = __builtin_amdgcn_mfma_f32_16x16x32_bf16(
            af[mt], bf[nt], acc[mt][nt], 0, 0, 0);
  }
  const float alpha = alphaPtr ? alphaPtr[0] : 1.0f;
#pragma unroll
  for (int mt = 0; mt < 4; ++mt)
#pragma unroll
    for (int nt = 0; nt < 4; ++nt)
#pragma unroll
      for (int r = 0; r < 4; ++r) {
        const int row = m0 + wm * 64 + mt * 16 + q * 4 + r;
        const int col = n0 + wn * 64 + nt * 16 + lm;
        const float vv = acc[mt][nt][r] * alpha;
        if (outBf16)
          ((unsigned short*)Cp)[(size_t)row * N + col] = f2bf(vv);
        else
          ((float*)Cp)[(size_t)row * N + col] = vv;
      }
}

// ---------------------------------------------------------------------------
// Transpose V slice of QKV: QKV[b*T+t][512+c] -> VT[b][c][t]. 64x64 tiles.
// ---------------------------------------------------------------------------
__global__ __launch_bounds__(256) void transpose_v(
    const unsigned short* __restrict__ QKV, unsigned short* __restrict__ VT) {
  __shared__ unsigned short tile[64][65];
  const int tb = blockIdx.x, cb = blockIdx.y, b = blockIdx.z;
  const int tid = threadIdx.x;
#pragma unroll
  for (int r2 = 0; r2 < 2; ++r2) {
    const int idx = r2 * 256 + tid;
    const int row = idx >> 3, p = idx & 7;
    const us8 v = *(const us8*)(QKV +
        ((size_t)(b * T_ + tb * 64 + row)) * 768 + 512 + cb * 64 + p * 8);
#pragma unroll
    for (int j = 0; j < 8; ++j) tile[row][p * 8 + j] = v[j];
  }
  __syncthreads();
#pragma unroll
  for (int r2 = 0; r2 < 2; ++r2) {
    const int idx = r2 * 256 + tid;
    const int c = idx >> 3, p = idx & 7;
    us8 v;
#pragma unroll
    for (int j = 0; j < 8; ++j) v[j] = tile[p * 8 + j][c];
    *(us8*)(VT + ((size_t)b * C_ + cb * 64 + c) * T_ + tb * 64 + p * 8) = v;
  }
}

// ---------------------------------------------------------------------------
// Windowed anti-causal decayed attention. t-tile 32, s-tile 64, 256 thr.
// K staged full (32KB [ch8][row64][64B]), V in two 16KB halves ([c256][64B]),
// all XOR-swizzled -> conflict-free frag reads. Ss stride 72 (2-way = free).
// 32 MFMA / 5 barriers per wave per s-tile. Grid 512, XCD-local t-ranges.
// (R3/R6-exact proven kernel.)
// ---------------------------------------------------------------------------
__global__ __launch_bounds__(256) void attn_mfma(
    const unsigned short* __restrict__ QKV, const unsigned short* __restrict__ VT,
    const float* __restrict__ dlp, unsigned short* __restrict__ R) {
  __shared__ __align__(16) unsigned short Kst[16384];  // 32KB
  __shared__ __align__(16) unsigned short Vst[8192];   // 16KB (V half)
  __shared__ __align__(16) unsigned short Ss[32 * 72]; // 4.5KB

  const int g = blockIdx.x;
  const int chunk = (g & 7) * 64 + (g >> 3);
  const int b = chunk >> 7;
  const int t0 = (chunk & 127) << 5;
  const int tid = threadIdx.x;
  const int w = tid >> 6, l = tid & 63, q = l >> 4, lm = l & 15;
  const float dec = 1.f / (1.f + __expf(-dlp[0]));
  const float l2d = log2f(dec);
  const unsigned short* QKVb = QKV + (size_t)b * T_ * 768;
  const int fsw = ((q + (lm >> 1)) & 3) * 16;

  // ---- stage Q [ch8][row32][64B] (16KB) swizzled, extract frags ----
  {
    const char* Qg = (const char*)(QKVb + (size_t)t0 * 768);
#pragma unroll
    for (int p = 0; p < 4; ++p) {
      const int o = (p * 256 + tid) * 16;
      const int ch = o >> 11, row = (o >> 6) & 31;
      const int clg = ((((o >> 4) & 3) - (row >> 1)) & 3) * 16;
      gld16(Qg + (size_t)row * 1536 + ch * 64 + clg, (char*)Kst + o);
    }
  }
  __syncthreads();
  bf16x8 qf[2][8];
#pragma unroll
  for (int mt = 0; mt < 2; ++mt)
#pragma unroll
    for (int ch = 0; ch < 8; ++ch)
      qf[mt][ch] = *(const bf16x8*)((const char*)Kst + ch * 2048 +
                                    (mt * 16 + lm) * 64 + fsw);

  const f32x4 zero4 = {0.f, 0.f, 0.f, 0.f};
  f32x4 acc[2][4];
#pragma unroll
  for (int i = 0; i < 2; ++i)
#pragma unroll
    for (int j = 0; j < 4; ++j) acc[i][j] = zero4;

  const int st0 = t0 >> 6;
  const int st1 = min(T_ / 64 - 1, (t0 + 31 + WINDOW) >> 6);
  const char* Kg = (const char*)QKVb + 512;  // K cols start at ushort 256
  const char* Vg = (const char*)(VT + (size_t)b * C_ * T_);

  for (int st = st0; st <= st1; ++st) {
    const int s0 = st << 6;
    __syncthreads();  // A: prior readers of Kst/Vst/Ss done
#pragma unroll
    for (int p = 0; p < 8; ++p) {  // K tile [ch8][row64][64B]
      const int o = (p * 256 + tid) * 16;
      const int ch = o >> 12, row = (o >> 6) & 63;
      const int clg = ((((o >> 4) & 3) - (row >> 1)) & 3) * 16;
      gld16(Kg + (size_t)(s0 + row) * 1536 + ch * 64 + clg, (char*)Kst + o);
    }
#pragma unroll
    for (int p = 0; p < 4; ++p) {  // V half 0: s0..s0+31
      const int o = (p * 256 + tid) * 16;
      const int c = o >> 6;
      const int clg8 = (((o >> 4) & 3) - (c >> 1)) & 3;
      gld16(Vg + ((size_t)c * T_ + s0 + clg8 * 8) * 2, (char*)Vst + o);
    }
    __syncthreads();  // B: K + Vh0 visible

    // ---- QK^T: wave w -> s-cols [s0+16w, s0+16w+16), both mt tiles ----
    f32x4 sc[2] = {zero4, zero4};
#pragma unroll
    for (int ch = 0; ch < 8; ++ch) {
      const bf16x8 kf = *(const bf16x8*)((const char*)Kst + ch * 4096 +
                                         (w * 16 + lm) * 64 + fsw);
      sc[0] = __builtin_amdgcn_mfma_f32_16x16x32_bf16(qf[0][ch], kf, sc[0], 0, 0, 0);
      sc[1] = __builtin_amdgcn_mfma_f32_16x16x32_bf16(qf[1][ch], kf, sc[1], 0, 0, 0);
    }
    // ---- decay*mask in C-layout, bf16 scores to LDS ----
    const int sg = s0 + w * 16 + lm;
#pragma unroll
    for (int mt = 0; mt < 2; ++mt)
#pragma unroll
      for (int r = 0; r < 4; ++r) {
        const int trow = t0 + mt * 16 + q * 4 + r;
        const int d = sg - trow;
        const float wgt = (d > 0) ? exp2f(l2d * (float)(d - 1)) : 0.f;
        Ss[(mt * 16 + q * 4 + r) * 72 + w * 16 + lm] = f2bf(sc[mt][r] * wgt);
      }
    __syncthreads();  // C: Ss visible
    bf16x8 sa[2][2];
#pragma unroll
    for (int m2 = 0; m2 < 2; ++m2)
#pragma unroll
      for (int kc2 = 0; kc2 < 2; ++kc2)
        sa[m2][kc2] = *(const bf16x8*)&Ss[(m2 * 16 + lm) * 72 + kc2 * 32 + q * 8];
    // ---- S*V, k-half 0: wave w -> channels 64w..64w+63 ----
#pragma unroll
    for (int n2 = 0; n2 < 4; ++n2) {
      const bf16x8 vf = *(const bf16x8*)((const char*)Vst +
                                         (w * 64 + n2 * 16 + lm) * 64 + fsw);
      acc[0][n2] = __builtin_amdgcn_mfma_f32_16x16x32_bf16(sa[0][0], vf, acc[0][n2], 0, 0, 0);
      acc[1][n2] = __builtin_amdgcn_mfma_f32_16x16x32_bf16(sa[1][0], vf, acc[1][n2], 0, 0, 0);
    }
    __syncthreads();  // D: Vh0 consumed
#pragma unroll
    for (int p = 0; p < 4; ++p) {  // V half 1: s0+32..s0+63
      const int o = (p * 256 + tid) * 16;
      const int c = o >> 6;
      const int clg8 = (((o >> 4) & 3) - (c >> 1)) & 3;
      gld16(Vg + ((size_t)c * T_ + s0 + 32 + clg8 * 8) * 2, (char*)Vst + o);
    }
    __syncthreads();  // E: Vh1 visible
#pragma unroll
    for (int n2 = 0; n2 < 4; ++n2) {
      const bf16x8 vf = *(const bf16x8*)((const char*)Vst +
                                         (w * 64 + n2 * 16 + lm) * 64 + fsw);
      acc[0][n2] = __builtin_amdgcn_mfma_f32_16x16x32_bf16(sa[0][1], vf, acc[0][n2], 0, 0, 0);
      acc[1][n2] = __builtin_amdgcn_mfma_f32_16x16x32_bf16(sa[1][1], vf, acc[1][n2], 0, 0, 0);
    }
  }
  // epilogue
#pragma unroll
  for (int m2 = 0; m2 < 2; ++m2)
#pragma unroll
    for (int n2 = 0; n2 < 4; ++n2)
#pragma unroll
      for (int r = 0; r < 4; ++r) {
        const int row = t0 + m2 * 16 + q * 4 + r;
        const int col = w * 64 + n2 * 16 + lm;
        R[((size_t)b * T_ + row) * C_ + col] = f2bf(acc[m2][n2][r]);
      }
}

// ---------------------------------------------------------------------------
extern "C" void kernel_launch(void* const* d_in, const int* in_sizes, int n_in,
                              void* d_out, int out_size, void* d_ws,
                              size_t ws_size, hipStream_t stream) {
  const float* x     = (const float*)d_in[0];
  const float* basis = (const float*)d_in[1];
  const float* qc    = (const float*)d_in[2];
  const float* kc    = (const float*)d_in[3];
  const float* vc    = (const float*)d_in[4];
  const float* oc    = (const float*)d_in[5];
  const float* dl    = (const float*)d_in[6];
  const float* osc   = (const float*)d_in[7];
  float* out = (float*)d_out;

  unsigned short* ws = (unsigned short*)d_ws;
  const size_t MSZ = (size_t)B_ * T_ * C_;                // 4.19M
  unsigned short* xb2  = ws;                              // [16384,256]
  unsigned short* W3   = xb2 + MSZ;                       // [768,256]
  unsigned short* bsT  = W3 + 768 * 256;                  // [256,1024]
  unsigned short* owb  = bsT + 256 * 1024;                // [1024,256]
  unsigned short* QKVb = owb + 1024 * 256;                // [B*T,768] q|k|v
  unsigned short* VTb  = QKVb + (size_t)B_ * T_ * 768;    // [B,256,T]
  unsigned short* Rb   = VTb + MSZ;                       // [B*T,256]

  prep_casts<<<dim3(96, 2), 256, 0, stream>>>(qc, kc, vc, basis, W3, bsT);
  weights_o<<<dim3(64), 256, 0, stream>>>(basis, oc, owb);
  // xb2 = x @ basis : [16384,1024](f32) x [256,1024]^T -> bf16 [16384,256]
  gemm_x_basis<<<dim3(1024), 256, 0, stream>>>(x, bsT, xb2);
  // fused QKV: [16384,256] x [768,256]^T -> bf16 [16384,768]
  gemm_bt_mfma<<<dim3(768), 256, 0, stream>>>(xb2, W3, QKVb, 256, 768, 6, 1,
                                              nullptr);
  transpose_v<<<dim3(T_ / 64, C_ / 64, B_), 256, 0, stream>>>(QKVb, VTb);
  attn_mfma<<<dim3((T_ / 32) * B_), 256, 0, stream>>>(QKVb, VTb, dl, Rb);
  // out = out_scale * R @ owb^T : [16384,256] x [1024,256]^T -> fp32
  gemm_bt_mfma<<<dim3(1024), 256, 0, stream>>>(Rb, owb, out, C_, V_, 8, 0, osc);
}

// Round 8
// 227.818 us; speedup vs baseline: 1.4629x; 1.0073x over previous
//
// AssociativeMemoryStep — Round 11.
// R11 = R6-exact pipeline except the front path: back to bf16-first.
//   cast_x (x -> xb bf16, pure BW) + gemm_xb (128x64-tile clone of the proven
//   all-gld16 gemm_bt_mfma, K=1024, grid 512) replaces the fp32-A
//   gemm_x_basis (R6/R7/R10 bracket its floor at 42.5-47.7us; the all-gld16
//   family measured ~2x better per-MFMA pace in R0).
// Pipeline: prep_casts (W3 | bsT) -> weights_o -> cast_x -> gemm_xb
//   xb2 = xb@bsT^T -> QKV = xb2@W3^T (gemm_bt_mfma) -> transpose_v -> attn
//   -> O-proj (gemm_bt_mfma).  QKVb aliases dead xb (ws 60MB <= verified 78).
// LDS XOR swizzle (64B rows): physical 16B chunk = (logical + (row>>1)) & 3.
//   gld16 dest lane-linear => *source* permuted; frag reads use
//   fsw=((q+(lm>>1))&3)*16.  (Verified involution, unchanged.)
// Window 512: decay^511 ~ 1.7e-11 relative -> exact truncation.
#include <hip/hip_runtime.h>
#include <math.h>
#include <stdint.h>

#define B_ 4
#define T_ 4096
#define V_ 1024
#define C_ 256
#define WINDOW 512

typedef __bf16 bf16x8 __attribute__((ext_vector_type(8)));
typedef float f32x4 __attribute__((ext_vector_type(4)));
typedef unsigned short us8 __attribute__((ext_vector_type(8)));

__device__ __forceinline__ void gld16(const void* g, void* l) {
  auto gp = reinterpret_cast<const __attribute__((address_space(1))) uint32_t*>(
      reinterpret_cast<uintptr_t>(g));
  auto lp = reinterpret_cast<__attribute__((address_space(3))) uint32_t*>(
      reinterpret_cast<uintptr_t>(l));
  __builtin_amdgcn_global_load_lds(gp, lp, 16, 0, 0);
}

__device__ __forceinline__ unsigned short f2bf(float f) {
  union { float f; unsigned u; } v; v.f = f;
  unsigned r = v.u + 0x7fffu + ((v.u >> 16) & 1u);  // RNE
  return (unsigned short)(r >> 16);
}

// ---------------------------------------------------------------------------
__global__ __launch_bounds__(256) void cast_x_bf16(
    const float* __restrict__ x, unsigned short* __restrict__ xb) {
  const size_t i = ((size_t)blockIdx.x * 256 + threadIdx.x) * 8;
  const float4 a = *(const float4*)(x + i);
  const float4 b = *(const float4*)(x + i + 4);
  us8 o;
  o[0] = f2bf(a.x); o[1] = f2bf(a.y); o[2] = f2bf(a.z); o[3] = f2bf(a.w);
  o[4] = f2bf(b.x); o[5] = f2bf(b.y); o[6] = f2bf(b.z); o[7] = f2bf(b.w);
  *(us8*)(xb + i) = o;
}

// ---------------------------------------------------------------------------
// prep_casts: y==0: W3[768,256] = bf16(concat(qc,kc,vc)) — raw coeffs.
//             y==1 (blocks 0..63): bsT[256,1024] = bf16(basis^T).
// ---------------------------------------------------------------------------
__global__ __launch_bounds__(256) void prep_casts(
    const float* __restrict__ qc, const float* __restrict__ kc,
    const float* __restrict__ vc, const float* __restrict__ basis,
    unsigned short* __restrict__ W3, unsigned short* __restrict__ bsT) {
  __shared__ unsigned short tile[64][65];
  const int tid = threadIdx.x;
  if (blockIdx.y == 0) {
    const size_t i = ((size_t)blockIdx.x * 256 + tid) * 8;  // < 196608
    const float* src = (i < 65536) ? qc + i
                     : (i < 131072) ? kc + (i - 65536) : vc + (i - 131072);
    const float4 a = *(const float4*)src;
    const float4 b = *(const float4*)(src + 4);
    us8 o;
    o[0] = f2bf(a.x); o[1] = f2bf(a.y); o[2] = f2bf(a.z); o[3] = f2bf(a.w);
    o[4] = f2bf(b.x); o[5] = f2bf(b.y); o[6] = f2bf(b.z); o[7] = f2bf(b.w);
    *(us8*)(W3 + i) = o;
  } else {
    if (blockIdx.x >= 64) return;
    const int rb = blockIdx.x >> 2, cb = blockIdx.x & 3;  // 16 x 4 tiles of 64
#pragma unroll
    for (int r2 = 0; r2 < 2; ++r2) {
      const int idx = r2 * 256 + tid;
      const int row = idx >> 3, p = idx & 7;
      const float4 a = *(const float4*)(basis + (size_t)(rb * 64 + row) * 256 +
                                        cb * 64 + p * 8);
      const float4 b = *(const float4*)(basis + (size_t)(rb * 64 + row) * 256 +
                                        cb * 64 + p * 8 + 4);
      tile[row][p * 8 + 0] = f2bf(a.x); tile[row][p * 8 + 1] = f2bf(a.y);
      tile[row][p * 8 + 2] = f2bf(a.z); tile[row][p * 8 + 3] = f2bf(a.w);
      tile[row][p * 8 + 4] = f2bf(b.x); tile[row][p * 8 + 5] = f2bf(b.y);
      tile[row][p * 8 + 6] = f2bf(b.z); tile[row][p * 8 + 7] = f2bf(b.w);
    }
    __syncthreads();
#pragma unroll
    for (int r2 = 0; r2 < 2; ++r2) {
      const int idx = r2 * 256 + tid;
      const int c = idx >> 3, p = idx & 7;
      us8 v;
#pragma unroll
      for (int j = 0; j < 8; ++j) v[j] = tile[p * 8 + j][c];
      *(us8*)(bsT + ((size_t)(cb * 64 + c)) * 1024 + rb * 64 + p * 8) = v;
    }
  }
}

// ---------------------------------------------------------------------------
// weights_o: owb[1024,256] = bf16(basis @ oc^T). Grid 64 (16 x 4 tiles of 64).
// ---------------------------------------------------------------------------
__global__ __launch_bounds__(256) void weights_o(
    const float* __restrict__ basis, const float* __restrict__ oc,
    unsigned short* __restrict__ owb) {
  const int bm = blockIdx.x >> 2, bn = blockIdx.x & 3;
  const int m0 = bm * 64, n0 = bn * 64;
  __shared__ float As[16][65];
  __shared__ float Bs[16][65];
  const int tid = threadIdx.x;
  const int tm = tid >> 4, tn = tid & 15;
  float acc[4][4] = {};
  for (int k0 = 0; k0 < 256; k0 += 16) {
#pragma unroll
    for (int r = 0; r < 4; ++r) {
      const int m = (tid >> 4) + 16 * r;
      As[tid & 15][m] = basis[(size_t)(m0 + m) * 256 + k0 + (tid & 15)];
      Bs[tid & 15][m] = oc[(size_t)(n0 + m) * 256 + k0 + (tid & 15)];
    }
    __syncthreads();
#pragma unroll
    for (int k = 0; k < 16; ++k) {
      float a[4], b[4];
#pragma unroll
      for (int i = 0; i < 4; ++i) a[i] = As[k][tm * 4 + i];
#pragma unroll
      for (int j = 0; j < 4; ++j) b[j] = Bs[k][tn * 4 + j];
#pragma unroll
      for (int i = 0; i < 4; ++i)
#pragma unroll
        for (int j = 0; j < 4; ++j) acc[i][j] += a[i] * b[j];
    }
    __syncthreads();
  }
#pragma unroll
  for (int i = 0; i < 4; ++i)
#pragma unroll
    for (int j = 0; j < 4; ++j)
      owb[(size_t)(m0 + tm * 4 + i) * 256 + n0 + tn * 4 + j] = f2bf(acc[i][j]);
}

// ---------------------------------------------------------------------------
// gemm_xb: xb2[16384,256] = xb(bf16)[16384,1024] @ bsT[256,1024]^T.
// 128m x 64n tile, BK=32, 256 thr = 4 waves (2m x 2n), wave 64x32, acc[4][2].
// All-gld16 staging (proven gemm_bt_mfma family; R0 pace 1035cy/16-MFMA-step).
// Grid 512 = 2 blocks/CU; xcd=g&7 owns m-tiles [16*xcd,+16) x 4 n-tiles.
// LDS 12KB: As 128x32, Bs 64x32, XOR-swizzled (identical constants).
// ---------------------------------------------------------------------------
__global__ __launch_bounds__(256) void gemm_xb(
    const unsigned short* __restrict__ A, const unsigned short* __restrict__ Bm,
    unsigned short* __restrict__ Cp) {
  __shared__ __align__(16) unsigned short As[128 * 32];  // 8KB
  __shared__ __align__(16) unsigned short Bs[64 * 32];   // 4KB
  const int tid = threadIdx.x;
  const int g = blockIdx.x;
  const int xcd = g & 7, loc = g >> 3;       // loc 0..63
  const int m0 = (xcd * 16 + (loc >> 2)) * 128;
  const int n0 = (loc & 3) * 64;
  const int w = tid >> 6, l = tid & 63, q = l >> 4, lm = l & 15;
  const int wm = w >> 1, wn = w & 1;
  const f32x4 zero4 = {0.f, 0.f, 0.f, 0.f};
  f32x4 acc[4][2];
#pragma unroll
  for (int i = 0; i < 4; ++i)
#pragma unroll
    for (int j = 0; j < 2; ++j) acc[i][j] = zero4;

  const int rowA = tid >> 2;
  const int cph = (tid & 3) * 16;                         // physical chunk
  const int clg = (((tid & 3) - (rowA >> 1)) & 3) * 16;   // logical source
  const int fsw = ((q + (lm >> 1)) & 3) * 16;             // frag-read swizzle

  for (int k0 = 0; k0 < 1024; k0 += 32) {
    __syncthreads();
    const char* Ag = (const char*)A + ((size_t)(m0 + rowA) * 1024 + k0) * 2 + clg;
    const char* Bg = (const char*)Bm + ((size_t)(n0 + rowA) * 1024 + k0) * 2 + clg;
    gld16(Ag, (char*)As + rowA * 64 + cph);
    gld16(Ag + (size_t)64 * 2048, (char*)As + (64 + rowA) * 64 + cph);
    gld16(Bg, (char*)Bs + rowA * 64 + cph);
    __syncthreads();
    bf16x8 af[4], bf[2];
#pragma unroll
    for (int mt = 0; mt < 4; ++mt)
      af[mt] = *(const bf16x8*)((const char*)As +
                                (wm * 64 + mt * 16 + lm) * 64 + fsw);
#pragma unroll
    for (int nt = 0; nt < 2; ++nt)
      bf[nt] = *(const bf16x8*)((const char*)Bs +
                                (wn * 32 + nt * 16 + lm) * 64 + fsw);
#pragma unroll
    for (int mt = 0; mt < 4; ++mt)
#pragma unroll
      for (int nt = 0; nt < 2; ++nt)
        acc[mt][nt] = __builtin_amdgcn_mfma_f32_16x16x32_bf16(
            af[mt], bf[nt], acc[mt][nt], 0, 0, 0);
  }
#pragma unroll
  for (int mt = 0; mt < 4; ++mt)
#pragma unroll
    for (int nt = 0; nt < 2; ++nt)
#pragma unroll
      for (int r = 0; r < 4; ++r) {
        const int row = m0 + wm * 64 + mt * 16 + q * 4 + r;
        const int col = n0 + wn * 32 + nt * 16 + lm;
        Cp[(size_t)row * 256 + col] = f2bf(acc[mt][nt][r]);
      }
}

// ---------------------------------------------------------------------------
// bf16 MFMA GEMM, C = alpha * A[M,K] * B[N,K]^T. 128x128 tile, BK=32.
// (R3-exact proven kernel.) 1D grid = nT*128 blocks; XCD swizzle: xcd=g&7
// owns m-tiles [16*xcd,16*xcd+16) x all n. LDS XOR-swizzled, conflict-free.
// ---------------------------------------------------------------------------
__global__ __launch_bounds__(256) void gemm_bt_mfma(
    const unsigned short* __restrict__ A, const unsigned short* __restrict__ Bm,
    void* __restrict__ Cp, int Kd, int N, int nT, int outBf16,
    const float* __restrict__ alphaPtr) {
  __shared__ __align__(16) unsigned short As[128 * 32];
  __shared__ __align__(16) unsigned short Bs[128 * 32];
  const int tid = threadIdx.x;
  const int g = blockIdx.x;
  const int xcd = g & 7, loc = g >> 3;
  const int n0 = (loc % nT) * 128;
  const int m0 = (xcd * 16 + loc / nT) * 128;
  const int w = tid >> 6, l = tid & 63, q = l >> 4, lm = l & 15;
  const int wm = w >> 1, wn = w & 1;
  const f32x4 zero4 = {0.f, 0.f, 0.f, 0.f};
  f32x4 acc[4][4];
#pragma unroll
  for (int i = 0; i < 4; ++i)
#pragma unroll
    for (int j = 0; j < 4; ++j) acc[i][j] = zero4;

  const int rowA = tid >> 2;
  const int cph = (tid & 3) * 16;                         // physical chunk
  const int clg = (((tid & 3) - (rowA >> 1)) & 3) * 16;   // logical source
  const int fsw = ((q + (lm >> 1)) & 3) * 16;             // frag-read swizzle

  for (int k0 = 0; k0 < Kd; k0 += 32) {
    __syncthreads();
    const char* Ag = (const char*)A + ((size_t)(m0 + rowA) * Kd + k0) * 2 + clg;
    const char* Bg = (const char*)Bm + ((size_t)(n0 + rowA) * Kd + k0) * 2 + clg;
    gld16(Ag, (char*)As + rowA * 64 + cph);
    gld16(Ag + (size_t)64 * Kd * 2, (char*)As + (64 + rowA) * 64 + cph);
    gld16(Bg, (char*)Bs + rowA * 64 + cph);
    gld16(Bg + (size_t)64 * Kd * 2, (char*)Bs + (64 + rowA) * 64 + cph);
    __syncthreads();
    bf16x8 af[4], bf[4];
#pragma unroll
    for (int mt = 0; mt < 4; ++mt)
      af[mt] = *(const bf16x8*)((const char*)As +
                                (wm * 64 + mt * 16 + lm) * 64 + fsw);
#pragma unroll
    for (int nt = 0; nt < 4; ++nt)
      bf[nt] = *(const bf16x8*)((const char*)Bs +
                                (wn * 64 + nt * 16 + lm) * 64 + fsw);
#pragma unroll
    for (int mt = 0; mt < 4; ++mt)
#pragma unroll
      for (int nt = 0; nt < 4; ++nt)
        acc[mt][nt] = __builtin_amdgcn_mfma_f32_16x16x32_bf16(
            af[mt], bf[nt], acc[mt][nt], 0, 0, 0);
  }
  const float alpha = alphaPtr ? alphaPtr[0] : 1.0f;
#pragma unroll
  for (int mt = 0; mt < 4; ++mt)
#pragma unroll
    for (int nt = 0; nt < 4; ++nt)
#pragma unroll
      for (int r = 0; r < 4; ++r) {
        const int row = m0 + wm * 64 + mt * 16 + q * 4 + r;
        const int col = n0 + wn * 64 + nt * 16 + lm;
        const float vv = acc[mt][nt][r] * alpha;
        if (outBf16)
          ((unsigned short*)Cp)[(size_t)row * N + col] = f2bf(vv);
        else
          ((float*)Cp)[(size_t)row * N + col] = vv;
      }
}

// ---------------------------------------------------------------------------
// Transpose V slice of QKV: QKV[b*T+t][512+c] -> VT[b][c][t]. 64x64 tiles.
// ---------------------------------------------------------------------------
__global__ __launch_bounds__(256) void transpose_v(
    const unsigned short* __restrict__ QKV, unsigned short* __restrict__ VT) {
  __shared__ unsigned short tile[64][65];
  const int tb = blockIdx.x, cb = blockIdx.y, b = blockIdx.z;
  const int tid = threadIdx.x;
#pragma unroll
  for (int r2 = 0; r2 < 2; ++r2) {
    const int idx = r2 * 256 + tid;
    const int row = idx >> 3, p = idx & 7;
    const us8 v = *(const us8*)(QKV +
        ((size_t)(b * T_ + tb * 64 + row)) * 768 + 512 + cb * 64 + p * 8);
#pragma unroll
    for (int j = 0; j < 8; ++j) tile[row][p * 8 + j] = v[j];
  }
  __syncthreads();
#pragma unroll
  for (int r2 = 0; r2 < 2; ++r2) {
    const int idx = r2 * 256 + tid;
    const int c = idx >> 3, p = idx & 7;
    us8 v;
#pragma unroll
    for (int j = 0; j < 8; ++j) v[j] = tile[p * 8 + j][c];
    *(us8*)(VT + ((size_t)b * C_ + cb * 64 + c) * T_ + tb * 64 + p * 8) = v;
  }
}

// ---------------------------------------------------------------------------
// Windowed anti-causal decayed attention. t-tile 32, s-tile 64, 256 thr.
// K staged full (32KB [ch8][row64][64B]), V in two 16KB halves ([c256][64B]),
// all XOR-swizzled -> conflict-free frag reads. Ss stride 72 (2-way = free).
// 32 MFMA / 5 barriers per wave per s-tile. Grid 512, XCD-local t-ranges.
// (R3/R6-exact proven kernel.)
// ---------------------------------------------------------------------------
__global__ __launch_bounds__(256) void attn_mfma(
    const unsigned short* __restrict__ QKV, const unsigned short* __restrict__ VT,
    const float* __restrict__ dlp, unsigned short* __restrict__ R) {
  __shared__ __align__(16) unsigned short Kst[16384];  // 32KB
  __shared__ __align__(16) unsigned short Vst[8192];   // 16KB (V half)
  __shared__ __align__(16) unsigned short Ss[32 * 72]; // 4.5KB

  const int g = blockIdx.x;
  const int chunk = (g & 7) * 64 + (g >> 3);
  const int b = chunk >> 7;
  const int t0 = (chunk & 127) << 5;
  const int tid = threadIdx.x;
  const int w = tid >> 6, l = tid & 63, q = l >> 4, lm = l & 15;
  const float dec = 1.f / (1.f + __expf(-dlp[0]));
  const float l2d = log2f(dec);
  const unsigned short* QKVb = QKV + (size_t)b * T_ * 768;
  const int fsw = ((q + (lm >> 1)) & 3) * 16;

  // ---- stage Q [ch8][row32][64B] (16KB) swizzled, extract frags ----
  {
    const char* Qg = (const char*)(QKVb + (size_t)t0 * 768);
#pragma unroll
    for (int p = 0; p < 4; ++p) {
      const int o = (p * 256 + tid) * 16;
      const int ch = o >> 11, row = (o >> 6) & 31;
      const int clg = ((((o >> 4) & 3) - (row >> 1)) & 3) * 16;
      gld16(Qg + (size_t)row * 1536 + ch * 64 + clg, (char*)Kst + o);
    }
  }
  __syncthreads();
  bf16x8 qf[2][8];
#pragma unroll
  for (int mt = 0; mt < 2; ++mt)
#pragma unroll
    for (int ch = 0; ch < 8; ++ch)
      qf[mt][ch] = *(const bf16x8*)((const char*)Kst + ch * 2048 +
                                    (mt * 16 + lm) * 64 + fsw);

  const f32x4 zero4 = {0.f, 0.f, 0.f, 0.f};
  f32x4 acc[2][4];
#pragma unroll
  for (int i = 0; i < 2; ++i)
#pragma unroll
    for (int j = 0; j < 4; ++j) acc[i][j] = zero4;

  const int st0 = t0 >> 6;
  const int st1 = min(T_ / 64 - 1, (t0 + 31 + WINDOW) >> 6);
  const char* Kg = (const char*)QKVb + 512;  // K cols start at ushort 256
  const char* Vg = (const char*)(VT + (size_t)b * C_ * T_);

  for (int st = st0; st <= st1; ++st) {
    const int s0 = st << 6;
    __syncthreads();  // A: prior readers of Kst/Vst/Ss done
#pragma unroll
    for (int p = 0; p < 8; ++p) {  // K tile [ch8][row64][64B]
      const int o = (p * 256 + tid) * 16;
      const int ch = o >> 12, row = (o >> 6) & 63;
      const int clg = ((((o >> 4) & 3) - (row >> 1)) & 3) * 16;
      gld16(Kg + (size_t)(s0 + row) * 1536 + ch * 64 + clg, (char*)Kst + o);
    }
#pragma unroll
    for (int p = 0; p < 4; ++p) {  // V half 0: s0..s0+31
      const int o = (p * 256 + tid) * 16;
      const int c = o >> 6;
      const int clg8 = (((o >> 4) & 3) - (c >> 1)) & 3;
      gld16(Vg + ((size_t)c * T_ + s0 + clg8 * 8) * 2, (char*)Vst + o);
    }
    __syncthreads();  // B: K + Vh0 visible

    // ---- QK^T: wave w -> s-cols [s0+16w, s0+16w+16), both mt tiles ----
    f32x4 sc[2] = {zero4, zero4};
#pragma unroll
    for (int ch = 0; ch < 8; ++ch) {
      const bf16x8 kf = *(const bf16x8*)((const char*)Kst + ch * 4096 +
                                         (w * 16 + lm) * 64 + fsw);
      sc[0] = __builtin_amdgcn_mfma_f32_16x16x32_bf16(qf[0][ch], kf, sc[0], 0, 0, 0);
      sc[1] = __builtin_amdgcn_mfma_f32_16x16x32_bf16(qf[1][ch], kf, sc[1], 0, 0, 0);
    }
    // ---- decay*mask in C-layout, bf16 scores to LDS ----
    const int sg = s0 + w * 16 + lm;
#pragma unroll
    for (int mt = 0; mt < 2; ++mt)
#pragma unroll
      for (int r = 0; r < 4; ++r) {
        const int trow = t0 + mt * 16 + q * 4 + r;
        const int d = sg - trow;
        const float wgt = (d > 0) ? exp2f(l2d * (float)(d - 1)) : 0.f;
        Ss[(mt * 16 + q * 4 + r) * 72 + w * 16 + lm] = f2bf(sc[mt][r] * wgt);
      }
    __syncthreads();  // C: Ss visible
    bf16x8 sa[2][2];
#pragma unroll
    for (int m2 = 0; m2 < 2; ++m2)
#pragma unroll
      for (int kc2 = 0; kc2 < 2; ++kc2)
        sa[m2][kc2] = *(const bf16x8*)&Ss[(m2 * 16 + lm) * 72 + kc2 * 32 + q * 8];
    // ---- S*V, k-half 0: wave w -> channels 64w..64w+63 ----
#pragma unroll
    for (int n2 = 0; n2 < 4; ++n2) {
      const bf16x8 vf = *(const bf16x8*)((const char*)Vst +
                                         (w * 64 + n2 * 16 + lm) * 64 + fsw);
      acc[0][n2] = __builtin_amdgcn_mfma_f32_16x16x32_bf16(sa[0][0], vf, acc[0][n2], 0, 0, 0);
      acc[1][n2] = __builtin_amdgcn_mfma_f32_16x16x32_bf16(sa[1][0], vf, acc[1][n2], 0, 0, 0);
    }
    __syncthreads();  // D: Vh0 consumed
#pragma unroll
    for (int p = 0; p < 4; ++p) {  // V half 1: s0+32..s0+63
      const int o = (p * 256 + tid) * 16;
      const int c = o >> 6;
      const int clg8 = (((o >> 4) & 3) - (c >> 1)) & 3;
      gld16(Vg + ((size_t)c * T_ + s0 + 32 + clg8 * 8) * 2, (char*)Vst + o);
    }
    __syncthreads();  // E: Vh1 visible
#pragma unroll
    for (int n2 = 0; n2 < 4; ++n2) {
      const bf16x8 vf = *(const bf16x8*)((const char*)Vst +
                                         (w * 64 + n2 * 16 + lm) * 64 + fsw);
      acc[0][n2] = __builtin_amdgcn_mfma_f32_16x16x32_bf16(sa[0][1], vf, acc[0][n2], 0, 0, 0);
      acc[1][n2] = __builtin_amdgcn_mfma_f32_16x16x32_bf16(sa[1][1], vf, acc[1][n2], 0, 0, 0);
    }
  }
  // epilogue
#pragma unroll
  for (int m2 = 0; m2 < 2; ++m2)
#pragma unroll
    for (int n2 = 0; n2 < 4; ++n2)
#pragma unroll
      for (int r = 0; r < 4; ++r) {
        const int row = t0 + m2 * 16 + q * 4 + r;
        const int col = w * 64 + n2 * 16 + lm;
        R[((size_t)b * T_ + row) * C_ + col] = f2bf(acc[m2][n2][r]);
      }
}

// ---------------------------------------------------------------------------
extern "C" void kernel_launch(void* const* d_in, const int* in_sizes, int n_in,
                              void* d_out, int out_size, void* d_ws,
                              size_t ws_size, hipStream_t stream) {
  const float* x     = (const float*)d_in[0];
  const float* basis = (const float*)d_in[1];
  const float* qc    = (const float*)d_in[2];
  const float* kc    = (const float*)d_in[3];
  const float* vc    = (const float*)d_in[4];
  const float* oc    = (const float*)d_in[5];
  const float* dl    = (const float*)d_in[6];
  const float* osc   = (const float*)d_in[7];
  float* out = (float*)d_out;

  unsigned short* ws = (unsigned short*)d_ws;
  const size_t XSZ = (size_t)B_ * T_ * V_;                // 16.78M
  const size_t MSZ = (size_t)B_ * T_ * C_;                // 4.19M
  // region0: xb [16384,1024]; QKVb aliases it (xb dead after gemm_xb).
  unsigned short* xb   = ws;
  unsigned short* QKVb = ws;                              // [B*T,768] alias
  unsigned short* xb2  = ws + XSZ;                        // [16384,256]
  unsigned short* W3   = xb2 + MSZ;                       // [768,256]
  unsigned short* bsT  = W3 + 768 * 256;                  // [256,1024]
  unsigned short* owb  = bsT + 256 * 1024;                // [1024,256]
  unsigned short* VTb  = owb + 1024 * 256;                // [B,256,T]
  unsigned short* Rb   = VTb + MSZ;                       // [B*T,256]

  prep_casts<<<dim3(96, 2), 256, 0, stream>>>(qc, kc, vc, basis, W3, bsT);
  weights_o<<<dim3(64), 256, 0, stream>>>(basis, oc, owb);
  cast_x_bf16<<<dim3(XSZ / (256 * 8)), 256, 0, stream>>>(x, xb);
  // xb2 = xb @ basis : [16384,1024] x [256,1024]^T -> bf16 [16384,256]
  gemm_xb<<<dim3(512), 256, 0, stream>>>(xb, bsT, xb2);
  // fused QKV: [16384,256] x [768,256]^T -> bf16 [16384,768] (over dead xb)
  gemm_bt_mfma<<<dim3(768), 256, 0, stream>>>(xb2, W3, QKVb, 256, 768, 6, 1,
                                              nullptr);
  transpose_v<<<dim3(T_ / 64, C_ / 64, B_), 256, 0, stream>>>(QKVb, VTb);
  attn_mfma<<<dim3((T_ / 32) * B_), 256, 0, stream>>>(QKVb, VTb, dl, Rb);
  // out = out_scale * R @ owb^T : [16384,256] x [1024,256]^T -> fp32
  gemm_bt_mfma<<<dim3(1024), 256, 0, stream>>>(Rb, owb, out, C_, V_, 8, 0, osc);
}